// Round 6
// baseline (462.478 us; speedup 1.0000x reference)
//
#include <hip/hip_runtime.h>
#include <hip/hip_bf16.h>

// GAT 2-layer forward on MI355X.
// CSR-by-dst build via two-level counting sort (no global atomics, dense
// writes) + single-pass pull aggregation (no-max softmax, logits computed
// once per edge-head, bpermute broadcast).
// GEMM1: bf16 MFMA (16x16x32); A-tile staged to LDS via async
// global_load_lds (width 16) to maximize memory-level parallelism.

#define F_IN 500
#define HEADS 8
#define HID 8
#define HD 64   // HEADS*HID
#define CLS 3
#define NEG 0.2f
#define EPSV 1e-16f
#define KPAD 512
#define SCB 512
#define LOG2E 1.44269504088896340736f

#define NBLK_H 128     // blocks in hist/scatter passes
#define NBKT_MAX 3136  // >= ceil(N/32)

typedef __attribute__((ext_vector_type(8))) short short8v;   // 8 bf16
typedef __attribute__((ext_vector_type(4))) float f32x4;

__device__ inline short bfs(float v) {
    __hip_bfloat16 b = __float2bfloat16(v);
    return *(short*)&b;
}

// ---------- edge_index dtype detection (int32 vs int64 little-endian) ----------
__global__ void k_detect(const int* ei, int* flag) {
    int z = 0;
    for (int i = 1; i < 16; i += 2) z += (ei[i] == 0) ? 1 : 0;
    *flag = (z == 8) ? 1 : 0;
}

__device__ inline int ld_edge(const void* ei, long idx, int is64) {
    return is64 ? (int)((const long long*)ei)[idx] : ((const int*)ei)[idx];
}

// ---------- W1 -> bf16, transposed [c][k] with k zero-padded to 512 ----------
__global__ void k_prepW(const float* __restrict__ W1, ushort* __restrict__ W1b) {
    int i = blockIdx.x * 256 + threadIdx.x;
    if (i >= HD * KPAD) return;
    int c = i >> 9, k = i & (KPAD - 1);
    float v = (k < F_IN) ? W1[k * HD + c] : 0.f;
    __hip_bfloat16 b = __float2bfloat16(v);
    W1b[i] = *(ushort*)&b;
}

// ---------- Layer-1 GEMM: h1[N,64] = x[N,500] @ W1[500,64], bf16 MFMA ----------
// Block: 256 threads = 4 waves; block tile 64 rows x 64 cols; wave w owns
// rows w*16..w*16+15. Per 32-k step the block stages x[64][32] (8 KB) into
// LDS via global_load_lds (2 issues of 16 B/lane per wave), then each lane
// ds_reads its 32 B A-fragment. B from pre-transposed bf16 W1b (L2-resident).
__global__ __launch_bounds__(256) void k_gemm1(const float* __restrict__ x,
        const ushort* __restrict__ W1b, float* __restrict__ h1, int N) {
    __shared__ float xs[64 * 32];   // 8 KB
    int t = threadIdx.x;
    int lane = t & 63;
    int w = t >> 6;
    int l16 = lane & 15, oct = lane >> 4;
    int rowb = blockIdx.x * 64;

    f32x4 acc0 = {0.f, 0.f, 0.f, 0.f};
    f32x4 acc1 = {0.f, 0.f, 0.f, 0.f};
    f32x4 acc2 = {0.f, 0.f, 0.f, 0.f};
    f32x4 acc3 = {0.f, 0.f, 0.f, 0.f};

    const ushort* Bl = W1b + (size_t)l16 * KPAD + oct * 8;

    // staging addresses (invariant parts)
    int tt0 = t, tt1 = t + 256;
    int srow0 = tt0 >> 3, sc0 = (tt0 & 7) * 4;
    int srow1 = tt1 >> 3, sc1 = (tt1 & 7) * 4;
    int gr0 = rowb + srow0; gr0 = (gr0 < N) ? gr0 : (N - 1);
    int gr1 = rowb + srow1; gr1 = (gr1 < N) ? gr1 : (N - 1);
    const float* sp0 = x + (long)gr0 * F_IN + sc0;
    const float* sp1 = x + (long)gr1 * F_IN + sc1;
    // wave-uniform LDS bases (HW adds lane*16 B)
    float* ld0 = &xs[(w * 64) * 4];
    float* ld1 = &xs[(256 + w * 64) * 4];
    const float* ap = &xs[(w * 16 + l16) * 32 + oct * 8];

    for (int ks = 0; ks < 15; ++ks) {
        const int k0 = ks * 32;
        __builtin_amdgcn_global_load_lds(
            (const __attribute__((address_space(1))) void*)(sp0 + k0),
            (__attribute__((address_space(3))) void*)ld0, 16, 0, 0);
        __builtin_amdgcn_global_load_lds(
            (const __attribute__((address_space(1))) void*)(sp1 + k0),
            (__attribute__((address_space(3))) void*)ld1, 16, 0, 0);
        __syncthreads();   // compiler emits vmcnt(0) drain before barrier
        short8v b0 = *reinterpret_cast<const short8v*>(Bl + k0);
        short8v b1 = *reinterpret_cast<const short8v*>(Bl + 16 * KPAD + k0);
        short8v b2 = *reinterpret_cast<const short8v*>(Bl + 32 * KPAD + k0);
        short8v b3 = *reinterpret_cast<const short8v*>(Bl + 48 * KPAD + k0);
        float4 x0 = *reinterpret_cast<const float4*>(ap);
        float4 x1 = *reinterpret_cast<const float4*>(ap + 4);
        short8v a;
        a[0] = bfs(x0.x); a[1] = bfs(x0.y); a[2] = bfs(x0.z); a[3] = bfs(x0.w);
        a[4] = bfs(x1.x); a[5] = bfs(x1.y); a[6] = bfs(x1.z); a[7] = bfs(x1.w);
        acc0 = __builtin_amdgcn_mfma_f32_16x16x32_bf16(a, b0, acc0, 0, 0, 0);
        acc1 = __builtin_amdgcn_mfma_f32_16x16x32_bf16(a, b1, acc1, 0, 0, 0);
        acc2 = __builtin_amdgcn_mfma_f32_16x16x32_bf16(a, b2, acc2, 0, 0, 0);
        acc3 = __builtin_amdgcn_mfma_f32_16x16x32_bf16(a, b3, acc3, 0, 0, 0);
        __syncthreads();   // protect xs from next step's staging
    }
    {   // tail k0 = 480, valid k < 500 (W1b zero-padded); direct guarded loads
        const int k0 = 480;
        int grow = rowb + w * 16 + l16;
        int rowc = (grow < N) ? grow : (N - 1);
        const float* xr = x + (long)rowc * F_IN;
        int kb = k0 + oct * 8;
        short8v a;
#pragma unroll
        for (int j = 0; j < 8; ++j)
            a[j] = bfs((kb + j < F_IN) ? xr[kb + j] : 0.f);
        short8v b0 = *reinterpret_cast<const short8v*>(Bl + k0);
        short8v b1 = *reinterpret_cast<const short8v*>(Bl + 16 * KPAD + k0);
        short8v b2 = *reinterpret_cast<const short8v*>(Bl + 32 * KPAD + k0);
        short8v b3 = *reinterpret_cast<const short8v*>(Bl + 48 * KPAD + k0);
        acc0 = __builtin_amdgcn_mfma_f32_16x16x32_bf16(a, b0, acc0, 0, 0, 0);
        acc1 = __builtin_amdgcn_mfma_f32_16x16x32_bf16(a, b1, acc1, 0, 0, 0);
        acc2 = __builtin_amdgcn_mfma_f32_16x16x32_bf16(a, b2, acc2, 0, 0, 0);
        acc3 = __builtin_amdgcn_mfma_f32_16x16x32_bf16(a, b3, acc3, 0, 0, 0);
    }
#pragma unroll
    for (int r = 0; r < 4; ++r) {
        int rr = rowb + w * 16 + oct * 4 + r;
        if (rr < N) {
            float* hp = h1 + (long)rr * HD + l16;
            hp[0]  = acc0[r];
            hp[16] = acc1[r];
            hp[32] = acc2[r];
            hp[48] = acc3[r];
        }
    }
}

// ---------- per-node attention logits (prescaled by log2(e)) + bf16 h1 copy ----------
__global__ void k_attlogits1(const float* __restrict__ h1,
        const float* __restrict__ asrc, const float* __restrict__ adst,
        float* __restrict__ als, float* __restrict__ ald,
        ushort* __restrict__ h1b, int N) {
    int t = blockIdx.x * 256 + threadIdx.x;
    if (t >= N * HEADS) return;
    int h = t & 7;
    const float* hp = &h1[(long)t * HID];
    float s1 = 0.f, s2 = 0.f;
    uint w[4];
#pragma unroll
    for (int d = 0; d < 4; d++) {
        float v0 = hp[2 * d], v1 = hp[2 * d + 1];
        s1 += v0 * asrc[h * HID + 2 * d] + v1 * asrc[h * HID + 2 * d + 1];
        s2 += v0 * adst[h * HID + 2 * d] + v1 * adst[h * HID + 2 * d + 1];
        __hip_bfloat16 b0 = __float2bfloat16(v0);
        __hip_bfloat16 b1 = __float2bfloat16(v1);
        w[d] = (uint)*(unsigned short*)&b0 | ((uint)*(unsigned short*)&b1 << 16);
    }
    als[t] = s1 * LOG2E; ald[t] = s2 * LOG2E;   // exp2 domain
    *reinterpret_cast<uint4*>(&h1b[(long)t * 8]) = make_uint4(w[0], w[1], w[2], w[3]);
}

// ================= CSR build: two-level counting sort =================

__global__ __launch_bounds__(256) void k_hist(const void* ei, int E, int N, int nbkt,
        int* __restrict__ ghist, const int* flag) {
    __shared__ int h[NBKT_MAX];
    int tot = E + N;
    int epb = (tot + NBLK_H - 1) / NBLK_H;
    int e0 = blockIdx.x * epb, e1 = min(tot, e0 + epb);
    for (int i = threadIdx.x; i < nbkt; i += 256) h[i] = 0;
    __syncthreads();
    int is64 = *flag;
    for (int e = e0 + threadIdx.x; e < e1; e += 256) {
        int dst = (e < E) ? ld_edge(ei, (long)E + e, is64) : (e - E);
        atomicAdd(&h[dst >> 5], 1);
    }
    __syncthreads();
    for (int i = threadIdx.x; i < nbkt; i += 256)
        ghist[blockIdx.x * nbkt + i] = h[i];
}

__global__ void k_bsum(const int* __restrict__ ghist, int* __restrict__ colsum, int nbkt) {
    int b = blockIdx.x * 256 + threadIdx.x;
    if (b >= nbkt) return;
    int s = 0;
    for (int i = 0; i < NBLK_H; i++) s += ghist[i * nbkt + b];
    colsum[b] = s;
}

__global__ __launch_bounds__(256) void k_bscan2(const int* __restrict__ colsum,
        int* __restrict__ boff, int nbkt) {
    __shared__ int part[256];
    int per = (nbkt + 255) / 256;
    int t = threadIdx.x;
    int lo = t * per, hi = min(nbkt, lo + per);
    int s = 0;
    for (int i = lo; i < hi; i++) s += colsum[i];
    part[t] = s;
    __syncthreads();
    for (int off = 1; off < 256; off <<= 1) {
        int v = (t >= off) ? part[t - off] : 0;
        __syncthreads();
        part[t] += v;
        __syncthreads();
    }
    int run = (t > 0) ? part[t - 1] : 0;
    for (int i = lo; i < hi; i++) { boff[i] = run; run += colsum[i]; }
    if (t == 255) boff[nbkt] = part[255];
}

__global__ void k_bapply(int* __restrict__ ghist, const int* __restrict__ boff, int nbkt) {
    int b = blockIdx.x * 256 + threadIdx.x;
    if (b >= nbkt) return;
    int run = boff[b];
    for (int i = 0; i < NBLK_H; i++) {
        int v = ghist[i * nbkt + b];
        ghist[i * nbkt + b] = run;
        run += v;
    }
}

__global__ __launch_bounds__(256) void k_scatter(const void* ei, int E, int N, int nbkt,
        const int* __restrict__ ghist, uint* __restrict__ pairs, const int* flag) {
    __shared__ int cur[NBKT_MAX];
    int tot = E + N;
    int epb = (tot + NBLK_H - 1) / NBLK_H;
    int e0 = blockIdx.x * epb, e1 = min(tot, e0 + epb);
    for (int i = threadIdx.x; i < nbkt; i += 256) cur[i] = ghist[blockIdx.x * nbkt + i];
    __syncthreads();
    int is64 = *flag;
    for (int e = e0 + threadIdx.x; e < e1; e += 256) {
        int src, dst;
        if (e < E) { src = ld_edge(ei, e, is64); dst = ld_edge(ei, (long)E + e, is64); }
        else { src = dst = e - E; }
        int pos = atomicAdd(&cur[dst >> 5], 1);
        pairs[pos] = ((uint)src << 5) | (uint)(dst & 31);
    }
}

__global__ __launch_bounds__(256) void k_deg2(const uint* __restrict__ pairs,
        const int* __restrict__ boff, int* __restrict__ deg, int N) {
    __shared__ int cnt[32];
    int b = blockIdx.x;
    if (threadIdx.x < 32) cnt[threadIdx.x] = 0;
    __syncthreads();
    int p0 = boff[b], p1 = boff[b + 1];
    for (int p = p0 + threadIdx.x; p < p1; p += 256)
        atomicAdd(&cnt[pairs[p] & 31], 1);
    __syncthreads();
    int n = b * 32 + threadIdx.x;
    if (threadIdx.x < 32 && n < N) deg[n] = cnt[threadIdx.x];
}

__global__ __launch_bounds__(SCB) void k_scan1(const int* deg, int* rowptr, int* bsum, int N) {
    __shared__ int s[SCB];
    int tid = threadIdx.x;
    int i = blockIdx.x * SCB + tid;
    int v = (i < N) ? deg[i] : 0;
    s[tid] = v;
    __syncthreads();
    for (int off = 1; off < SCB; off <<= 1) {
        int tv = (tid >= off) ? s[tid - off] : 0;
        __syncthreads();
        s[tid] += tv;
        __syncthreads();
    }
    if (i < N) rowptr[i] = s[tid] - v;
    if (tid == SCB - 1) bsum[blockIdx.x] = s[tid];
}

__global__ void k_scan2(int* bsum, int* rowptr, int nb, int N) {
    int run = 0;
    for (int i = 0; i < nb; i++) { int v = bsum[i]; bsum[i] = run; run += v; }
    rowptr[N] = run;
}

__global__ void k_scan3(int* rowptr, const int* bsum, int N) {
    int i = blockIdx.x * SCB + threadIdx.x;
    if (i < N) rowptr[i] += bsum[blockIdx.x];
}

__global__ __launch_bounds__(256) void k_fill2(const uint* __restrict__ pairs,
        const int* __restrict__ boff, const int* __restrict__ rowptr,
        int* __restrict__ csr, int N) {
    __shared__ int base[32];
    __shared__ int cur[32];
    int b = blockIdx.x;
    int n0 = b * 32;
    if (threadIdx.x < 32) {
        int n = n0 + threadIdx.x;
        base[threadIdx.x] = (n < N) ? rowptr[n] : 0;
        cur[threadIdx.x] = 0;
    }
    __syncthreads();
    int p0 = boff[b], p1 = boff[b + 1];
    for (int p = p0 + threadIdx.x; p < p1; p += 256) {
        uint v = pairs[p];
        int lo = v & 31;
        int pos = base[lo] + atomicAdd(&cur[lo], 1);
        csr[pos] = (int)(v >> 5);
    }
}

// ---------- Layer-1 pull aggregation (single pass, no-max softmax) ----------
__global__ __launch_bounds__(256) void k_agg1(const int* __restrict__ rowptr,
        const int* __restrict__ csr, const ushort* __restrict__ h1b,
        const float* __restrict__ als, const float* __restrict__ ald,
        const float* __restrict__ b1, float* __restrict__ hact, int N) {
    int n = blockIdx.x * 4 + (threadIdx.x >> 6);
    if (n >= N) return;
    int lane = threadIdx.x & 63;
    int rs = rowptr[n], re = rowptr[n + 1];
    int h = lane & 7;        // head (logit role)
    int es = lane >> 3;      // edge slot (logit role); also my head (accum role)
    float aldh = ald[n * HEADS + h];
    int bpa = es * 4;        // bpermute byte addr base
    float acc = 0.f, den = 0.f;

    for (int jb = rs; jb < re; jb += 8) {
        int eidx = jb + es;
        bool valid = (eidx < re);
        int s_own = valid ? csr[eidx] : 0;
        float e = valid ? (als[s_own * HEADS + h] + aldh) : -1e30f;
        e = fmaxf(e, NEG * e);          // leaky relu (log2 domain, scale>0)
        float p = exp2f(e);
#pragma unroll
        for (int eg = 0; eg < 8; ++eg) {
            float pe = __int_as_float(
                __builtin_amdgcn_ds_bpermute(bpa + eg * 32, __float_as_int(p)));
            int se = __builtin_amdgcn_readlane(s_own, eg * 8);
            ushort u = h1b[(long)se * HD + lane];
            acc += pe * __bfloat162float(*(const __hip_bfloat16*)&u);
            den += pe;
        }
    }
    float o = acc / (den + EPSV) + b1[lane];
    o = (o > 0.f) ? o : __expf(o) - 1.f;   // ELU
    hact[(long)n * HD + lane] = o;
}

// ---------- Layer-2 GEMM [N,64]x[64,3] + logits (wave per node) ----------
__global__ __launch_bounds__(256) void k_gemm2(const float* __restrict__ hact,
        const float* __restrict__ W2, const float* __restrict__ as2,
        const float* __restrict__ ad2, float* __restrict__ h2,
        float* __restrict__ als2, float* __restrict__ ald2, int N) {
    int n = blockIdx.x * 4 + (threadIdx.x >> 6);
    if (n >= N) return;
    int lane = threadIdx.x & 63;
    float hv = hact[(long)n * HD + lane];
    float p0 = hv * W2[lane * CLS + 0];
    float p1 = hv * W2[lane * CLS + 1];
    float p2 = hv * W2[lane * CLS + 2];
#pragma unroll
    for (int off = 32; off > 0; off >>= 1) {
        p0 += __shfl_down(p0, off);
        p1 += __shfl_down(p1, off);
        p2 += __shfl_down(p2, off);
    }
    if (lane == 0) {
        h2[n * CLS + 0] = p0; h2[n * CLS + 1] = p1; h2[n * CLS + 2] = p2;
        als2[n] = p0 * as2[0] + p1 * as2[1] + p2 * as2[2];
        ald2[n] = p0 * ad2[0] + p1 * ad2[1] + p2 * ad2[2];
    }
}

// ---------- Layer-2 pull aggregation + bias + log_softmax ----------
__global__ __launch_bounds__(256) void k_agg2(const int* __restrict__ rowptr,
        const int* __restrict__ csr, const float* __restrict__ h2,
        const float* __restrict__ als2v, const float* __restrict__ ald2v,
        const float* __restrict__ b2, float* __restrict__ out, int N) {
    int n = blockIdx.x * 4 + (threadIdx.x >> 6);
    if (n >= N) return;
    int lane = threadIdx.x & 63;
    float aldv = ald2v[n];
    int rs = rowptr[n], re = rowptr[n + 1];
    float m = -1e30f, sum = 0.f, a0 = 0.f, a1 = 0.f, a2 = 0.f;
    for (int j = rs + lane; j < re; j += 64) {
        int s = csr[j];
        float e = als2v[s] + aldv;
        e = (e >= 0.f) ? e : NEG * e;
        float nm = fmaxf(m, e);
        float sc = __expf(m - nm);
        float p = __expf(e - nm);
        sum = sum * sc + p;
        a0 = a0 * sc + p * h2[s * CLS + 0];
        a1 = a1 * sc + p * h2[s * CLS + 1];
        a2 = a2 * sc + p * h2[s * CLS + 2];
        m = nm;
    }
    float M = m;
#pragma unroll
    for (int off = 1; off < 64; off <<= 1) M = fmaxf(M, __shfl_xor(M, off));
    float sc = __expf(m - M);
    sum *= sc; a0 *= sc; a1 *= sc; a2 *= sc;
#pragma unroll
    for (int off = 1; off < 64; off <<= 1) {
        sum += __shfl_xor(sum, off);
        a0 += __shfl_xor(a0, off);
        a1 += __shfl_xor(a1, off);
        a2 += __shfl_xor(a2, off);
    }
    if (lane == 0) {
        float d = sum + EPSV;
        float v0 = a0 / d + b2[0], v1 = a1 / d + b2[1], v2 = a2 / d + b2[2];
        float mx = fmaxf(v0, fmaxf(v1, v2));
        float se = __expf(v0 - mx) + __expf(v1 - mx) + __expf(v2 - mx);
        float ls = mx + __logf(se);
        out[n * CLS + 0] = v0; out[n * CLS + 1] = v1; out[n * CLS + 2] = v2;
        long o2 = (long)N * CLS;
        out[o2 + n * CLS + 0] = v0 - ls;
        out[o2 + n * CLS + 1] = v1 - ls;
        out[o2 + n * CLS + 2] = v2 - ls;
    }
}

extern "C" void kernel_launch(void* const* d_in, const int* in_sizes, int n_in,
                              void* d_out, int out_size, void* d_ws, size_t ws_size,
                              hipStream_t stream) {
    const float* x   = (const float*)d_in[0];
    const void*  ei  = d_in[1];
    const float* W1  = (const float*)d_in[2];
    const float* as1 = (const float*)d_in[3];
    const float* ad1 = (const float*)d_in[4];
    const float* b1  = (const float*)d_in[5];
    const float* W2  = (const float*)d_in[6];
    const float* as2 = (const float*)d_in[7];
    const float* ad2 = (const float*)d_in[8];
    const float* b2  = (const float*)d_in[9];
    int N = in_sizes[0] / F_IN;
    int E = in_sizes[1] / 2;
    int tot = E + N;
    int nbkt = (N + 31) >> 5;

    char* w = (char*)d_ws;
    auto alloc = [&](size_t bytes) -> char* {
        char* p = w; w += (bytes + 255) & ~size_t(255); return p;
    };
    float*  h1     = (float*)alloc((size_t)N * HD * 4);   // dead after attlogits1
    ushort* h1b    = (ushort*)alloc((size_t)N * HD * 2);
    float*  hact   = (float*)alloc((size_t)N * HD * 4);
    float*  als1   = (float*)alloc((size_t)N * HEADS * 4);
    float*  ald1   = (float*)alloc((size_t)N * HEADS * 4);
    int*    rowptr = (int*)alloc((size_t)(N + 1) * 4);
    int*    deg    = (int*)alloc((size_t)N * 4);
    int nb = (N + SCB - 1) / SCB;
    int*    bsum   = (int*)alloc((size_t)nb * 4);
    int*    csr    = (int*)alloc((size_t)tot * 4);
    float*  h2     = (float*)alloc((size_t)N * CLS * 4);
    float*  als2   = (float*)alloc((size_t)N * 4);
    float*  ald2   = (float*)alloc((size_t)N * 4);
    ushort* W1b    = (ushort*)alloc((size_t)HD * KPAD * 2);
    int*    flag   = (int*)alloc(256);

    // CSR-build scratch aliases h1 (dead after attlogits1, same-stream ordered).
    char* ov = (char*)h1;
    uint* pairs  = (uint*)ov;                      ov += ((size_t)tot * 4 + 255) & ~size_t(255);
    int*  ghist  = (int*)ov;                       ov += ((size_t)NBLK_H * nbkt * 4 + 255) & ~size_t(255);
    int*  colsum = (int*)ov;                       ov += ((size_t)nbkt * 4 + 255) & ~size_t(255);
    int*  boff   = (int*)ov;                       ov += ((size_t)(nbkt + 1) * 4 + 255) & ~size_t(255);

    k_detect<<<1, 1, 0, stream>>>((const int*)ei, flag);
    k_prepW<<<(HD * KPAD + 255) / 256, 256, 0, stream>>>(W1, W1b);
    k_gemm1<<<(N + 63) / 64, 256, 0, stream>>>(x, W1b, h1, N);
    k_attlogits1<<<(N * HEADS + 255) / 256, 256, 0, stream>>>(h1, as1, ad1, als1, ald1, h1b, N);
    // ---- CSR build
    k_hist<<<NBLK_H, 256, 0, stream>>>(ei, E, N, nbkt, ghist, flag);
    k_bsum<<<(nbkt + 255) / 256, 256, 0, stream>>>(ghist, colsum, nbkt);
    k_bscan2<<<1, 256, 0, stream>>>(colsum, boff, nbkt);
    k_bapply<<<(nbkt + 255) / 256, 256, 0, stream>>>(ghist, boff, nbkt);
    k_scatter<<<NBLK_H, 256, 0, stream>>>(ei, E, N, nbkt, ghist, pairs, flag);
    k_deg2<<<nbkt, 256, 0, stream>>>(pairs, boff, deg, N);
    k_scan1<<<nb, SCB, 0, stream>>>(deg, rowptr, bsum, N);
    k_scan2<<<1, 1, 0, stream>>>(bsum, rowptr, nb, N);
    k_scan3<<<nb, SCB, 0, stream>>>(rowptr, bsum, N);
    k_fill2<<<nbkt, 256, 0, stream>>>(pairs, boff, rowptr, csr, N);
    // ---- aggregation / layer 2
    k_agg1<<<(N + 3) / 4, 256, 0, stream>>>(rowptr, csr, h1b, als1, ald1, b1, hact, N);
    k_gemm2<<<(N + 3) / 4, 256, 0, stream>>>(hact, W2, as2, ad2, h2, als2, ald2, N);
    k_agg2<<<(N + 3) / 4, 256, 0, stream>>>(rowptr, csr, h2, als2, ald2, b2, (float*)d_out, N);
}

// Round 7
// 428.631 us; speedup vs baseline: 1.0790x; 1.0790x over previous
//
#include <hip/hip_runtime.h>
#include <hip/hip_bf16.h>

// GAT 2-layer forward on MI355X.
// CSR-by-dst build via two-level counting sort + single-pass pull aggregation.
// GEMM1: bf16 MFMA, double-buffered LDS staging. A staged with pre-swizzled
// global source (linear LDS dest, XOR-swizzled reads -> 2-way banks); B
// pre-transposed to contiguous per-step slices and staged coalesced.

#define F_IN 500
#define HEADS 8
#define HID 8
#define HD 64   // HEADS*HID
#define CLS 3
#define NEG 0.2f
#define EPSV 1e-16f
#define SCB 512
#define LOG2E 1.44269504088896340736f

#define NBLK_H 128     // blocks in hist/scatter passes
#define NBKT_MAX 3136  // >= ceil(N/32)

typedef __attribute__((ext_vector_type(8))) short short8v;   // 8 bf16
typedef __attribute__((ext_vector_type(4))) float f32x4;

__device__ inline short bfs(float v) {
    __hip_bfloat16 b = __float2bfloat16(v);
    return *(short*)&b;
}

// ---------- edge_index dtype detection (int32 vs int64 little-endian) ----------
__global__ void k_detect(const int* ei, int* flag) {
    int z = 0;
    for (int i = 1; i < 16; i += 2) z += (ei[i] == 0) ? 1 : 0;
    *flag = (z == 8) ? 1 : 0;
}

__device__ inline int ld_edge(const void* ei, long idx, int is64) {
    return is64 ? (int)((const long long*)ei)[idx] : ((const int*)ei)[idx];
}

// ---------- W1 -> bf16 slices W1b2[ks][c][kk], kk pre-swizzled ----------
// Slice ks (4 KB) holds B for k-range [ks*32, ks*32+32). Within a c-row
// (64 B = 4 chunks of 16 B), stored chunk p contains logical chunk
// q = p ^ ((c>>1)&3). Zero-padded for k >= 500.
__global__ void k_prepW(const float* __restrict__ W1, ushort* __restrict__ W1b2) {
    int i = blockIdx.x * 256 + threadIdx.x;
    if (i >= 16 * 64 * 32) return;
    int ks = i >> 11;
    int c = (i >> 5) & 63;
    int st = i & 31;
    int q = (st >> 3) ^ ((c >> 1) & 3);
    int k = ks * 32 + q * 8 + (st & 7);
    float v = (k < F_IN) ? W1[k * HD + c] : 0.f;
    __hip_bfloat16 b = __float2bfloat16(v);
    W1b2[i] = *(ushort*)&b;
}

// ---------- Layer-1 GEMM: h1[N,64] = x[N,500] @ W1[500,64], bf16 MFMA ----------
// Block: 256 threads = 4 waves; tile 64 rows x 64 cols; wave w owns rows
// w*16..+15. Double-buffered: stage(ks+1) || compute(ks), 1 barrier/step.
// LDS: A[2][64 rows][128 B] at 0/8192 (f32, chunk-swizzled via source),
//      B[2][64 c][64 B]     at 16384/20480 (bf16, pre-swizzled in global).
__device__ __forceinline__ void g1_stage(const float* __restrict__ x,
        const ushort* __restrict__ W1b2, char* smem, int buf, int ks,
        int rowb, int N, int lane, int w) {
    const int k0 = ks * 32;
    // B: wave w stages its 1 KB quarter of the contiguous 4 KB slice
    {
        const ushort* srcB = W1b2 + ks * 2048 + (w * 64 + lane) * 8;
        char* dstB = smem + 16384 + buf * 4096 + w * 1024;
        __builtin_amdgcn_global_load_lds(
            (const __attribute__((address_space(1))) void*)srcB,
            (__attribute__((address_space(3))) void*)dstB, 16, 0, 0);
    }
#pragma unroll
    for (int i = 0; i < 2; ++i) {
        int vt = i * 256 + w * 64 + lane;     // 0..511 -> (row, chunk-slot)
        int row = vt >> 3;
        int c = (vt & 7) ^ (row & 7);         // pre-swizzled source chunk
        int ke = k0 + c * 4; if (ke > 496) ke = 496;   // stay inside row
        int rowg = rowb + row; if (rowg >= N) rowg = N - 1;
        const float* srcA = x + (long)rowg * F_IN + ke;
        char* dstA = smem + buf * 8192 + i * 4096 + w * 1024;
        __builtin_amdgcn_global_load_lds(
            (const __attribute__((address_space(1))) void*)srcA,
            (__attribute__((address_space(3))) void*)dstA, 16, 0, 0);
    }
}

__global__ __launch_bounds__(256) void k_gemm1(const float* __restrict__ x,
        const ushort* __restrict__ W1b2, float* __restrict__ h1, int N) {
    __shared__ char smem[24576];
    int t = threadIdx.x;
    int lane = t & 63;
    int w = t >> 6;
    int l16 = lane & 15, oct = lane >> 4;
    int rowb = blockIdx.x * 64;

    f32x4 acc0 = {0.f, 0.f, 0.f, 0.f};
    f32x4 acc1 = {0.f, 0.f, 0.f, 0.f};
    f32x4 acc2 = {0.f, 0.f, 0.f, 0.f};
    f32x4 acc3 = {0.f, 0.f, 0.f, 0.f};

    g1_stage(x, W1b2, smem, 0, 0, rowb, N, lane, w);
    __syncthreads();

    int rl = w * 16 + l16;
    int asw = l16 & 7;          // A chunk swizzle
    int bsw = (l16 >> 1) & 3;   // B chunk swizzle (same for all 4 col-blocks)

    for (int ks = 0; ks < 16; ++ks) {
        int cur = ks & 1;
        if (ks < 15)
            g1_stage(x, W1b2, smem, cur ^ 1, ks + 1, rowb, N, lane, w);
        const char* Ab = smem + cur * 8192;
        const char* Bb = smem + 16384 + cur * 4096;
        float4 x0 = *reinterpret_cast<const float4*>(
            Ab + rl * 128 + ((2 * oct + 0) ^ asw) * 16);
        float4 x1 = *reinterpret_cast<const float4*>(
            Ab + rl * 128 + ((2 * oct + 1) ^ asw) * 16);
        short8v a;
        a[0] = bfs(x0.x); a[1] = bfs(x0.y); a[2] = bfs(x0.z); a[3] = bfs(x0.w);
        a[4] = bfs(x1.x); a[5] = bfs(x1.y); a[6] = bfs(x1.z); a[7] = bfs(x1.w);
        short8v b0 = *reinterpret_cast<const short8v*>(
            Bb + (0 * 16 + l16) * 64 + (oct ^ bsw) * 16);
        short8v b1 = *reinterpret_cast<const short8v*>(
            Bb + (1 * 16 + l16) * 64 + (oct ^ bsw) * 16);
        short8v b2 = *reinterpret_cast<const short8v*>(
            Bb + (2 * 16 + l16) * 64 + (oct ^ bsw) * 16);
        short8v b3 = *reinterpret_cast<const short8v*>(
            Bb + (3 * 16 + l16) * 64 + (oct ^ bsw) * 16);
        acc0 = __builtin_amdgcn_mfma_f32_16x16x32_bf16(a, b0, acc0, 0, 0, 0);
        acc1 = __builtin_amdgcn_mfma_f32_16x16x32_bf16(a, b1, acc1, 0, 0, 0);
        acc2 = __builtin_amdgcn_mfma_f32_16x16x32_bf16(a, b2, acc2, 0, 0, 0);
        acc3 = __builtin_amdgcn_mfma_f32_16x16x32_bf16(a, b3, acc3, 0, 0, 0);
        __syncthreads();   // drains vmcnt (next buf written) + read-before-overwrite
    }
#pragma unroll
    for (int r = 0; r < 4; ++r) {
        int rr = rowb + w * 16 + oct * 4 + r;
        if (rr < N) {
            float* hp = h1 + (long)rr * HD + l16;
            hp[0]  = acc0[r];
            hp[16] = acc1[r];
            hp[32] = acc2[r];
            hp[48] = acc3[r];
        }
    }
}

// ---------- per-node attention logits (prescaled by log2(e)) + bf16 h1 copy ----------
__global__ void k_attlogits1(const float* __restrict__ h1,
        const float* __restrict__ asrc, const float* __restrict__ adst,
        float* __restrict__ als, float* __restrict__ ald,
        ushort* __restrict__ h1b, int N) {
    int t = blockIdx.x * 256 + threadIdx.x;
    if (t >= N * HEADS) return;
    int h = t & 7;
    const float* hp = &h1[(long)t * HID];
    float s1 = 0.f, s2 = 0.f;
    uint w[4];
#pragma unroll
    for (int d = 0; d < 4; d++) {
        float v0 = hp[2 * d], v1 = hp[2 * d + 1];
        s1 += v0 * asrc[h * HID + 2 * d] + v1 * asrc[h * HID + 2 * d + 1];
        s2 += v0 * adst[h * HID + 2 * d] + v1 * adst[h * HID + 2 * d + 1];
        __hip_bfloat16 b0 = __float2bfloat16(v0);
        __hip_bfloat16 b1 = __float2bfloat16(v1);
        w[d] = (uint)*(unsigned short*)&b0 | ((uint)*(unsigned short*)&b1 << 16);
    }
    als[t] = s1 * LOG2E; ald[t] = s2 * LOG2E;   // exp2 domain
    *reinterpret_cast<uint4*>(&h1b[(long)t * 8]) = make_uint4(w[0], w[1], w[2], w[3]);
}

// ================= CSR build: two-level counting sort =================

__global__ __launch_bounds__(256) void k_hist(const void* ei, int E, int N, int nbkt,
        int* __restrict__ ghist, const int* flag) {
    __shared__ int h[NBKT_MAX];
    int tot = E + N;
    int epb = (tot + NBLK_H - 1) / NBLK_H;
    int e0 = blockIdx.x * epb, e1 = min(tot, e0 + epb);
    for (int i = threadIdx.x; i < nbkt; i += 256) h[i] = 0;
    __syncthreads();
    int is64 = *flag;
    for (int e = e0 + threadIdx.x; e < e1; e += 256) {
        int dst = (e < E) ? ld_edge(ei, (long)E + e, is64) : (e - E);
        atomicAdd(&h[dst >> 5], 1);
    }
    __syncthreads();
    for (int i = threadIdx.x; i < nbkt; i += 256)
        ghist[blockIdx.x * nbkt + i] = h[i];
}

__global__ void k_bsum(const int* __restrict__ ghist, int* __restrict__ colsum, int nbkt) {
    int b = blockIdx.x * 256 + threadIdx.x;
    if (b >= nbkt) return;
    int s = 0;
    for (int i = 0; i < NBLK_H; i++) s += ghist[i * nbkt + b];
    colsum[b] = s;
}

__global__ __launch_bounds__(256) void k_bscan2(const int* __restrict__ colsum,
        int* __restrict__ boff, int nbkt) {
    __shared__ int part[256];
    int per = (nbkt + 255) / 256;
    int t = threadIdx.x;
    int lo = t * per, hi = min(nbkt, lo + per);
    int s = 0;
    for (int i = lo; i < hi; i++) s += colsum[i];
    part[t] = s;
    __syncthreads();
    for (int off = 1; off < 256; off <<= 1) {
        int v = (t >= off) ? part[t - off] : 0;
        __syncthreads();
        part[t] += v;
        __syncthreads();
    }
    int run = (t > 0) ? part[t - 1] : 0;
    for (int i = lo; i < hi; i++) { boff[i] = run; run += colsum[i]; }
    if (t == 255) boff[nbkt] = part[255];
}

__global__ void k_bapply(int* __restrict__ ghist, const int* __restrict__ boff, int nbkt) {
    int b = blockIdx.x * 256 + threadIdx.x;
    if (b >= nbkt) return;
    int run = boff[b];
    for (int i = 0; i < NBLK_H; i++) {
        int v = ghist[i * nbkt + b];
        ghist[i * nbkt + b] = run;
        run += v;
    }
}

__global__ __launch_bounds__(256) void k_scatter(const void* ei, int E, int N, int nbkt,
        const int* __restrict__ ghist, uint* __restrict__ pairs, const int* flag) {
    __shared__ int cur[NBKT_MAX];
    int tot = E + N;
    int epb = (tot + NBLK_H - 1) / NBLK_H;
    int e0 = blockIdx.x * epb, e1 = min(tot, e0 + epb);
    for (int i = threadIdx.x; i < nbkt; i += 256) cur[i] = ghist[blockIdx.x * nbkt + i];
    __syncthreads();
    int is64 = *flag;
    for (int e = e0 + threadIdx.x; e < e1; e += 256) {
        int src, dst;
        if (e < E) { src = ld_edge(ei, e, is64); dst = ld_edge(ei, (long)E + e, is64); }
        else { src = dst = e - E; }
        int pos = atomicAdd(&cur[dst >> 5], 1);
        pairs[pos] = ((uint)src << 5) | (uint)(dst & 31);
    }
}

__global__ __launch_bounds__(256) void k_deg2(const uint* __restrict__ pairs,
        const int* __restrict__ boff, int* __restrict__ deg, int N) {
    __shared__ int cnt[32];
    int b = blockIdx.x;
    if (threadIdx.x < 32) cnt[threadIdx.x] = 0;
    __syncthreads();
    int p0 = boff[b], p1 = boff[b + 1];
    for (int p = p0 + threadIdx.x; p < p1; p += 256)
        atomicAdd(&cnt[pairs[p] & 31], 1);
    __syncthreads();
    int n = b * 32 + threadIdx.x;
    if (threadIdx.x < 32 && n < N) deg[n] = cnt[threadIdx.x];
}

__global__ __launch_bounds__(SCB) void k_scan1(const int* deg, int* rowptr, int* bsum, int N) {
    __shared__ int s[SCB];
    int tid = threadIdx.x;
    int i = blockIdx.x * SCB + tid;
    int v = (i < N) ? deg[i] : 0;
    s[tid] = v;
    __syncthreads();
    for (int off = 1; off < SCB; off <<= 1) {
        int tv = (tid >= off) ? s[tid - off] : 0;
        __syncthreads();
        s[tid] += tv;
        __syncthreads();
    }
    if (i < N) rowptr[i] = s[tid] - v;
    if (tid == SCB - 1) bsum[blockIdx.x] = s[tid];
}

__global__ void k_scan2(int* bsum, int* rowptr, int nb, int N) {
    int run = 0;
    for (int i = 0; i < nb; i++) { int v = bsum[i]; bsum[i] = run; run += v; }
    rowptr[N] = run;
}

__global__ void k_scan3(int* rowptr, const int* bsum, int N) {
    int i = blockIdx.x * SCB + threadIdx.x;
    if (i < N) rowptr[i] += bsum[blockIdx.x];
}

__global__ __launch_bounds__(256) void k_fill2(const uint* __restrict__ pairs,
        const int* __restrict__ boff, const int* __restrict__ rowptr,
        int* __restrict__ csr, int N) {
    __shared__ int base[32];
    __shared__ int cur[32];
    int b = blockIdx.x;
    int n0 = b * 32;
    if (threadIdx.x < 32) {
        int n = n0 + threadIdx.x;
        base[threadIdx.x] = (n < N) ? rowptr[n] : 0;
        cur[threadIdx.x] = 0;
    }
    __syncthreads();
    int p0 = boff[b], p1 = boff[b + 1];
    for (int p = p0 + threadIdx.x; p < p1; p += 256) {
        uint v = pairs[p];
        int lo = v & 31;
        int pos = base[lo] + atomicAdd(&cur[lo], 1);
        csr[pos] = (int)(v >> 5);
    }
}

// ---------- Layer-1 pull aggregation (single pass, no-max softmax) ----------
__global__ __launch_bounds__(256) void k_agg1(const int* __restrict__ rowptr,
        const int* __restrict__ csr, const ushort* __restrict__ h1b,
        const float* __restrict__ als, const float* __restrict__ ald,
        const float* __restrict__ b1, float* __restrict__ hact, int N) {
    int n = blockIdx.x * 4 + (threadIdx.x >> 6);
    if (n >= N) return;
    int lane = threadIdx.x & 63;
    int rs = rowptr[n], re = rowptr[n + 1];
    int h = lane & 7;        // head (logit role)
    int es = lane >> 3;      // edge slot (logit role); also my head (accum role)
    float aldh = ald[n * HEADS + h];
    int bpa = es * 4;        // bpermute byte addr base
    float acc = 0.f, den = 0.f;

    for (int jb = rs; jb < re; jb += 8) {
        int eidx = jb + es;
        bool valid = (eidx < re);
        int s_own = valid ? csr[eidx] : 0;
        float e = valid ? (als[s_own * HEADS + h] + aldh) : -1e30f;
        e = fmaxf(e, NEG * e);          // leaky relu (log2 domain, scale>0)
        float p = exp2f(e);
#pragma unroll
        for (int eg = 0; eg < 8; ++eg) {
            float pe = __int_as_float(
                __builtin_amdgcn_ds_bpermute(bpa + eg * 32, __float_as_int(p)));
            int se = __builtin_amdgcn_readlane(s_own, eg * 8);
            ushort u = h1b[(long)se * HD + lane];
            acc += pe * __bfloat162float(*(const __hip_bfloat16*)&u);
            den += pe;
        }
    }
    float o = acc / (den + EPSV) + b1[lane];
    o = (o > 0.f) ? o : __expf(o) - 1.f;   // ELU
    hact[(long)n * HD + lane] = o;
}

// ---------- Layer-2 GEMM [N,64]x[64,3] + logits (wave per node) ----------
__global__ __launch_bounds__(256) void k_gemm2(const float* __restrict__ hact,
        const float* __restrict__ W2, const float* __restrict__ as2,
        const float* __restrict__ ad2, float* __restrict__ h2,
        float* __restrict__ als2, float* __restrict__ ald2, int N) {
    int n = blockIdx.x * 4 + (threadIdx.x >> 6);
    if (n >= N) return;
    int lane = threadIdx.x & 63;
    float hv = hact[(long)n * HD + lane];
    float p0 = hv * W2[lane * CLS + 0];
    float p1 = hv * W2[lane * CLS + 1];
    float p2 = hv * W2[lane * CLS + 2];
#pragma unroll
    for (int off = 32; off > 0; off >>= 1) {
        p0 += __shfl_down(p0, off);
        p1 += __shfl_down(p1, off);
        p2 += __shfl_down(p2, off);
    }
    if (lane == 0) {
        h2[n * CLS + 0] = p0; h2[n * CLS + 1] = p1; h2[n * CLS + 2] = p2;
        als2[n] = p0 * as2[0] + p1 * as2[1] + p2 * as2[2];
        ald2[n] = p0 * ad2[0] + p1 * ad2[1] + p2 * ad2[2];
    }
}

// ---------- Layer-2 pull aggregation + bias + log_softmax ----------
__global__ __launch_bounds__(256) void k_agg2(const int* __restrict__ rowptr,
        const int* __restrict__ csr, const float* __restrict__ h2,
        const float* __restrict__ als2v, const float* __restrict__ ald2v,
        const float* __restrict__ b2, float* __restrict__ out, int N) {
    int n = blockIdx.x * 4 + (threadIdx.x >> 6);
    if (n >= N) return;
    int lane = threadIdx.x & 63;
    float aldv = ald2v[n];
    int rs = rowptr[n], re = rowptr[n + 1];
    float m = -1e30f, sum = 0.f, a0 = 0.f, a1 = 0.f, a2 = 0.f;
    for (int j = rs + lane; j < re; j += 64) {
        int s = csr[j];
        float e = als2v[s] + aldv;
        e = (e >= 0.f) ? e : NEG * e;
        float nm = fmaxf(m, e);
        float sc = __expf(m - nm);
        float p = __expf(e - nm);
        sum = sum * sc + p;
        a0 = a0 * sc + p * h2[s * CLS + 0];
        a1 = a1 * sc + p * h2[s * CLS + 1];
        a2 = a2 * sc + p * h2[s * CLS + 2];
        m = nm;
    }
    float M = m;
#pragma unroll
    for (int off = 1; off < 64; off <<= 1) M = fmaxf(M, __shfl_xor(M, off));
    float sc = __expf(m - M);
    sum *= sc; a0 *= sc; a1 *= sc; a2 *= sc;
#pragma unroll
    for (int off = 1; off < 64; off <<= 1) {
        sum += __shfl_xor(sum, off);
        a0 += __shfl_xor(a0, off);
        a1 += __shfl_xor(a1, off);
        a2 += __shfl_xor(a2, off);
    }
    if (lane == 0) {
        float d = sum + EPSV;
        float v0 = a0 / d + b2[0], v1 = a1 / d + b2[1], v2 = a2 / d + b2[2];
        float mx = fmaxf(v0, fmaxf(v1, v2));
        float se = __expf(v0 - mx) + __expf(v1 - mx) + __expf(v2 - mx);
        float ls = mx + __logf(se);
        out[n * CLS + 0] = v0; out[n * CLS + 1] = v1; out[n * CLS + 2] = v2;
        long o2 = (long)N * CLS;
        out[o2 + n * CLS + 0] = v0 - ls;
        out[o2 + n * CLS + 1] = v1 - ls;
        out[o2 + n * CLS + 2] = v2 - ls;
    }
}

extern "C" void kernel_launch(void* const* d_in, const int* in_sizes, int n_in,
                              void* d_out, int out_size, void* d_ws, size_t ws_size,
                              hipStream_t stream) {
    const float* x   = (const float*)d_in[0];
    const void*  ei  = d_in[1];
    const float* W1  = (const float*)d_in[2];
    const float* as1 = (const float*)d_in[3];
    const float* ad1 = (const float*)d_in[4];
    const float* b1  = (const float*)d_in[5];
    const float* W2  = (const float*)d_in[6];
    const float* as2 = (const float*)d_in[7];
    const float* ad2 = (const float*)d_in[8];
    const float* b2  = (const float*)d_in[9];
    int N = in_sizes[0] / F_IN;
    int E = in_sizes[1] / 2;
    int tot = E + N;
    int nbkt = (N + 31) >> 5;

    char* w = (char*)d_ws;
    auto alloc = [&](size_t bytes) -> char* {
        char* p = w; w += (bytes + 255) & ~size_t(255); return p;
    };
    float*  h1     = (float*)alloc((size_t)N * HD * 4);   // dead after attlogits1
    ushort* h1b    = (ushort*)alloc((size_t)N * HD * 2);
    float*  hact   = (float*)alloc((size_t)N * HD * 4);
    float*  als1   = (float*)alloc((size_t)N * HEADS * 4);
    float*  ald1   = (float*)alloc((size_t)N * HEADS * 4);
    int*    rowptr = (int*)alloc((size_t)(N + 1) * 4);
    int*    deg    = (int*)alloc((size_t)N * 4);
    int nb = (N + SCB - 1) / SCB;
    int*    bsum   = (int*)alloc((size_t)nb * 4);
    int*    csr    = (int*)alloc((size_t)tot * 4);
    float*  h2     = (float*)alloc((size_t)N * CLS * 4);
    float*  als2   = (float*)alloc((size_t)N * 4);
    float*  ald2   = (float*)alloc((size_t)N * 4);
    ushort* W1b2   = (ushort*)alloc((size_t)16 * 64 * 32 * 2);
    int*    flag   = (int*)alloc(256);

    // CSR-build scratch aliases h1 (dead after attlogits1, same-stream ordered).
    char* ov = (char*)h1;
    uint* pairs  = (uint*)ov;                      ov += ((size_t)tot * 4 + 255) & ~size_t(255);
    int*  ghist  = (int*)ov;                       ov += ((size_t)NBLK_H * nbkt * 4 + 255) & ~size_t(255);
    int*  colsum = (int*)ov;                       ov += ((size_t)nbkt * 4 + 255) & ~size_t(255);
    int*  boff   = (int*)ov;                       ov += ((size_t)(nbkt + 1) * 4 + 255) & ~size_t(255);

    k_detect<<<1, 1, 0, stream>>>((const int*)ei, flag);
    k_prepW<<<(16 * 64 * 32 + 255) / 256, 256, 0, stream>>>(W1, W1b2);
    k_gemm1<<<(N + 63) / 64, 256, 0, stream>>>(x, W1b2, h1, N);
    k_attlogits1<<<(N * HEADS + 255) / 256, 256, 0, stream>>>(h1, as1, ad1, als1, ald1, h1b, N);
    // ---- CSR build
    k_hist<<<NBLK_H, 256, 0, stream>>>(ei, E, N, nbkt, ghist, flag);
    k_bsum<<<(nbkt + 255) / 256, 256, 0, stream>>>(ghist, colsum, nbkt);
    k_bscan2<<<1, 256, 0, stream>>>(colsum, boff, nbkt);
    k_bapply<<<(nbkt + 255) / 256, 256, 0, stream>>>(ghist, boff, nbkt);
    k_scatter<<<NBLK_H, 256, 0, stream>>>(ei, E, N, nbkt, ghist, pairs, flag);
    k_deg2<<<nbkt, 256, 0, stream>>>(pairs, boff, deg, N);
    k_scan1<<<nb, SCB, 0, stream>>>(deg, rowptr, bsum, N);
    k_scan2<<<1, 1, 0, stream>>>(bsum, rowptr, nb, N);
    k_scan3<<<nb, SCB, 0, stream>>>(rowptr, bsum, N);
    k_fill2<<<nbkt, 256, 0, stream>>>(pairs, boff, rowptr, csr, N);
    // ---- aggregation / layer 2
    k_agg1<<<(N + 3) / 4, 256, 0, stream>>>(rowptr, csr, h1b, als1, ald1, b1, hact, N);
    k_gemm2<<<(N + 3) / 4, 256, 0, stream>>>(hact, W2, as2, ad2, h2, als2, ald2, N);
    k_agg2<<<(N + 3) / 4, 256, 0, stream>>>(rowptr, csr, h2, als2, ald2, b2, (float*)d_out, N);
}

// Round 8
// 410.449 us; speedup vs baseline: 1.1268x; 1.0443x over previous
//
#include <hip/hip_runtime.h>
#include <hip/hip_bf16.h>

// GAT 2-layer forward on MI355X.
// CSR-by-dst build via two-level counting sort + single-pass pull aggregation.
// agg1: lane=(edge-slot,head); logit p is lane-local (HID==8 -> head owns its
// 8 dims); 16 B uint4 gathers; shfl_xor reduce over slots. No bpermute.
// GEMM1: bf16 MFMA, double-buffered LDS staging, swizzled (R6).

#define F_IN 500
#define HEADS 8
#define HID 8
#define HD 64   // HEADS*HID
#define CLS 3
#define NEG 0.2f
#define EPSV 1e-16f
#define SCB 512
#define LOG2E 1.44269504088896340736f

#define NBLK_H 128     // blocks in hist/scatter passes
#define NBKT_MAX 3136  // >= ceil(N/32)

typedef __attribute__((ext_vector_type(8))) short short8v;   // 8 bf16
typedef __attribute__((ext_vector_type(4))) float f32x4;

__device__ inline short bfs(float v) {
    __hip_bfloat16 b = __float2bfloat16(v);
    return *(short*)&b;
}

// ---------- edge_index dtype detection (int32 vs int64 little-endian) ----------
__global__ void k_detect(const int* ei, int* flag) {
    int z = 0;
    for (int i = 1; i < 16; i += 2) z += (ei[i] == 0) ? 1 : 0;
    *flag = (z == 8) ? 1 : 0;
}

__device__ inline int ld_edge(const void* ei, long idx, int is64) {
    return is64 ? (int)((const long long*)ei)[idx] : ((const int*)ei)[idx];
}

// ---------- W1 -> bf16 slices W1b2[ks][c][kk], kk pre-swizzled ----------
__global__ void k_prepW(const float* __restrict__ W1, ushort* __restrict__ W1b2) {
    int i = blockIdx.x * 256 + threadIdx.x;
    if (i >= 16 * 64 * 32) return;
    int ks = i >> 11;
    int c = (i >> 5) & 63;
    int st = i & 31;
    int q = (st >> 3) ^ ((c >> 1) & 3);
    int k = ks * 32 + q * 8 + (st & 7);
    float v = (k < F_IN) ? W1[k * HD + c] : 0.f;
    __hip_bfloat16 b = __float2bfloat16(v);
    W1b2[i] = *(ushort*)&b;
}

// ---------- Layer-1 GEMM (unchanged from R6) ----------
__device__ __forceinline__ void g1_stage(const float* __restrict__ x,
        const ushort* __restrict__ W1b2, char* smem, int buf, int ks,
        int rowb, int N, int lane, int w) {
    const int k0 = ks * 32;
    {
        const ushort* srcB = W1b2 + ks * 2048 + (w * 64 + lane) * 8;
        char* dstB = smem + 16384 + buf * 4096 + w * 1024;
        __builtin_amdgcn_global_load_lds(
            (const __attribute__((address_space(1))) void*)srcB,
            (__attribute__((address_space(3))) void*)dstB, 16, 0, 0);
    }
#pragma unroll
    for (int i = 0; i < 2; ++i) {
        int vt = i * 256 + w * 64 + lane;
        int row = vt >> 3;
        int c = (vt & 7) ^ (row & 7);
        int ke = k0 + c * 4; if (ke > 496) ke = 496;
        int rowg = rowb + row; if (rowg >= N) rowg = N - 1;
        const float* srcA = x + (long)rowg * F_IN + ke;
        char* dstA = smem + buf * 8192 + i * 4096 + w * 1024;
        __builtin_amdgcn_global_load_lds(
            (const __attribute__((address_space(1))) void*)srcA,
            (__attribute__((address_space(3))) void*)dstA, 16, 0, 0);
    }
}

__global__ __launch_bounds__(256) void k_gemm1(const float* __restrict__ x,
        const ushort* __restrict__ W1b2, float* __restrict__ h1, int N) {
    __shared__ char smem[24576];
    int t = threadIdx.x;
    int lane = t & 63;
    int w = t >> 6;
    int l16 = lane & 15, oct = lane >> 4;
    int rowb = blockIdx.x * 64;

    f32x4 acc0 = {0.f, 0.f, 0.f, 0.f};
    f32x4 acc1 = {0.f, 0.f, 0.f, 0.f};
    f32x4 acc2 = {0.f, 0.f, 0.f, 0.f};
    f32x4 acc3 = {0.f, 0.f, 0.f, 0.f};

    g1_stage(x, W1b2, smem, 0, 0, rowb, N, lane, w);
    __syncthreads();

    int rl = w * 16 + l16;
    int asw = l16 & 7;
    int bsw = (l16 >> 1) & 3;

    for (int ks = 0; ks < 16; ++ks) {
        int cur = ks & 1;
        if (ks < 15)
            g1_stage(x, W1b2, smem, cur ^ 1, ks + 1, rowb, N, lane, w);
        const char* Ab = smem + cur * 8192;
        const char* Bb = smem + 16384 + cur * 4096;
        float4 x0 = *reinterpret_cast<const float4*>(
            Ab + rl * 128 + ((2 * oct + 0) ^ asw) * 16);
        float4 x1 = *reinterpret_cast<const float4*>(
            Ab + rl * 128 + ((2 * oct + 1) ^ asw) * 16);
        short8v a;
        a[0] = bfs(x0.x); a[1] = bfs(x0.y); a[2] = bfs(x0.z); a[3] = bfs(x0.w);
        a[4] = bfs(x1.x); a[5] = bfs(x1.y); a[6] = bfs(x1.z); a[7] = bfs(x1.w);
        short8v b0 = *reinterpret_cast<const short8v*>(
            Bb + (0 * 16 + l16) * 64 + (oct ^ bsw) * 16);
        short8v b1 = *reinterpret_cast<const short8v*>(
            Bb + (1 * 16 + l16) * 64 + (oct ^ bsw) * 16);
        short8v b2 = *reinterpret_cast<const short8v*>(
            Bb + (2 * 16 + l16) * 64 + (oct ^ bsw) * 16);
        short8v b3 = *reinterpret_cast<const short8v*>(
            Bb + (3 * 16 + l16) * 64 + (oct ^ bsw) * 16);
        acc0 = __builtin_amdgcn_mfma_f32_16x16x32_bf16(a, b0, acc0, 0, 0, 0);
        acc1 = __builtin_amdgcn_mfma_f32_16x16x32_bf16(a, b1, acc1, 0, 0, 0);
        acc2 = __builtin_amdgcn_mfma_f32_16x16x32_bf16(a, b2, acc2, 0, 0, 0);
        acc3 = __builtin_amdgcn_mfma_f32_16x16x32_bf16(a, b3, acc3, 0, 0, 0);
        __syncthreads();
    }
#pragma unroll
    for (int r = 0; r < 4; ++r) {
        int rr = rowb + w * 16 + oct * 4 + r;
        if (rr < N) {
            float* hp = h1 + (long)rr * HD + l16;
            hp[0]  = acc0[r];
            hp[16] = acc1[r];
            hp[32] = acc2[r];
            hp[48] = acc3[r];
        }
    }
}

// ---------- per-node attention logits (prescaled by log2(e)) + bf16 h1 copy ----------
__global__ void k_attlogits1(const float* __restrict__ h1,
        const float* __restrict__ asrc, const float* __restrict__ adst,
        float* __restrict__ als, float* __restrict__ ald,
        ushort* __restrict__ h1b, int N) {
    int t = blockIdx.x * 256 + threadIdx.x;
    if (t >= N * HEADS) return;
    int h = t & 7;
    const float* hp = &h1[(long)t * HID];
    float s1 = 0.f, s2 = 0.f;
    uint w[4];
#pragma unroll
    for (int d = 0; d < 4; d++) {
        float v0 = hp[2 * d], v1 = hp[2 * d + 1];
        s1 += v0 * asrc[h * HID + 2 * d] + v1 * asrc[h * HID + 2 * d + 1];
        s2 += v0 * adst[h * HID + 2 * d] + v1 * adst[h * HID + 2 * d + 1];
        __hip_bfloat16 b0 = __float2bfloat16(v0);
        __hip_bfloat16 b1 = __float2bfloat16(v1);
        w[d] = (uint)*(unsigned short*)&b0 | ((uint)*(unsigned short*)&b1 << 16);
    }
    als[t] = s1 * LOG2E; ald[t] = s2 * LOG2E;   // exp2 domain
    *reinterpret_cast<uint4*>(&h1b[(long)t * 8]) = make_uint4(w[0], w[1], w[2], w[3]);
}

// ================= CSR build: two-level counting sort =================

__global__ __launch_bounds__(256) void k_hist(const void* ei, int E, int N, int nbkt,
        int* __restrict__ ghist, const int* flag) {
    __shared__ int h[NBKT_MAX];
    int tot = E + N;
    int epb = (tot + NBLK_H - 1) / NBLK_H;
    int e0 = blockIdx.x * epb, e1 = min(tot, e0 + epb);
    for (int i = threadIdx.x; i < nbkt; i += 256) h[i] = 0;
    __syncthreads();
    int is64 = *flag;
    for (int e = e0 + threadIdx.x; e < e1; e += 256) {
        int dst = (e < E) ? ld_edge(ei, (long)E + e, is64) : (e - E);
        atomicAdd(&h[dst >> 5], 1);
    }
    __syncthreads();
    for (int i = threadIdx.x; i < nbkt; i += 256)
        ghist[blockIdx.x * nbkt + i] = h[i];
}

__global__ void k_bsum(const int* __restrict__ ghist, int* __restrict__ colsum, int nbkt) {
    int b = blockIdx.x * 256 + threadIdx.x;
    if (b >= nbkt) return;
    int s = 0;
    for (int i = 0; i < NBLK_H; i++) s += ghist[i * nbkt + b];
    colsum[b] = s;
}

__global__ __launch_bounds__(256) void k_bscan2(const int* __restrict__ colsum,
        int* __restrict__ boff, int nbkt) {
    __shared__ int part[256];
    int per = (nbkt + 255) / 256;
    int t = threadIdx.x;
    int lo = t * per, hi = min(nbkt, lo + per);
    int s = 0;
    for (int i = lo; i < hi; i++) s += colsum[i];
    part[t] = s;
    __syncthreads();
    for (int off = 1; off < 256; off <<= 1) {
        int v = (t >= off) ? part[t - off] : 0;
        __syncthreads();
        part[t] += v;
        __syncthreads();
    }
    int run = (t > 0) ? part[t - 1] : 0;
    for (int i = lo; i < hi; i++) { boff[i] = run; run += colsum[i]; }
    if (t == 255) boff[nbkt] = part[255];
}

__global__ void k_bapply(int* __restrict__ ghist, const int* __restrict__ boff, int nbkt) {
    int b = blockIdx.x * 256 + threadIdx.x;
    if (b >= nbkt) return;
    int run = boff[b];
    for (int i = 0; i < NBLK_H; i++) {
        int v = ghist[i * nbkt + b];
        ghist[i * nbkt + b] = run;
        run += v;
    }
}

__global__ __launch_bounds__(256) void k_scatter(const void* ei, int E, int N, int nbkt,
        const int* __restrict__ ghist, uint* __restrict__ pairs, const int* flag) {
    __shared__ int cur[NBKT_MAX];
    int tot = E + N;
    int epb = (tot + NBLK_H - 1) / NBLK_H;
    int e0 = blockIdx.x * epb, e1 = min(tot, e0 + epb);
    for (int i = threadIdx.x; i < nbkt; i += 256) cur[i] = ghist[blockIdx.x * nbkt + i];
    __syncthreads();
    int is64 = *flag;
    for (int e = e0 + threadIdx.x; e < e1; e += 256) {
        int src, dst;
        if (e < E) { src = ld_edge(ei, e, is64); dst = ld_edge(ei, (long)E + e, is64); }
        else { src = dst = e - E; }
        int pos = atomicAdd(&cur[dst >> 5], 1);
        pairs[pos] = ((uint)src << 5) | (uint)(dst & 31);
    }
}

__global__ __launch_bounds__(256) void k_deg2(const uint* __restrict__ pairs,
        const int* __restrict__ boff, int* __restrict__ deg, int N) {
    __shared__ int cnt[32];
    int b = blockIdx.x;
    if (threadIdx.x < 32) cnt[threadIdx.x] = 0;
    __syncthreads();
    int p0 = boff[b], p1 = boff[b + 1];
    for (int p = p0 + threadIdx.x; p < p1; p += 256)
        atomicAdd(&cnt[pairs[p] & 31], 1);
    __syncthreads();
    int n = b * 32 + threadIdx.x;
    if (threadIdx.x < 32 && n < N) deg[n] = cnt[threadIdx.x];
}

__global__ __launch_bounds__(SCB) void k_scan1(const int* deg, int* rowptr, int* bsum, int N) {
    __shared__ int s[SCB];
    int tid = threadIdx.x;
    int i = blockIdx.x * SCB + tid;
    int v = (i < N) ? deg[i] : 0;
    s[tid] = v;
    __syncthreads();
    for (int off = 1; off < SCB; off <<= 1) {
        int tv = (tid >= off) ? s[tid - off] : 0;
        __syncthreads();
        s[tid] += tv;
        __syncthreads();
    }
    if (i < N) rowptr[i] = s[tid] - v;
    if (tid == SCB - 1) bsum[blockIdx.x] = s[tid];
}

__global__ void k_scan2(int* bsum, int* rowptr, int nb, int N) {
    int run = 0;
    for (int i = 0; i < nb; i++) { int v = bsum[i]; bsum[i] = run; run += v; }
    rowptr[N] = run;
}

__global__ void k_scan3(int* rowptr, const int* bsum, int N) {
    int i = blockIdx.x * SCB + threadIdx.x;
    if (i < N) rowptr[i] += bsum[blockIdx.x];
}

__global__ __launch_bounds__(256) void k_fill2(const uint* __restrict__ pairs,
        const int* __restrict__ boff, const int* __restrict__ rowptr,
        int* __restrict__ csr, int N) {
    __shared__ int base[32];
    __shared__ int cur[32];
    int b = blockIdx.x;
    int n0 = b * 32;
    if (threadIdx.x < 32) {
        int n = n0 + threadIdx.x;
        base[threadIdx.x] = (n < N) ? rowptr[n] : 0;
        cur[threadIdx.x] = 0;
    }
    __syncthreads();
    int p0 = boff[b], p1 = boff[b + 1];
    for (int p = p0 + threadIdx.x; p < p1; p += 256) {
        uint v = pairs[p];
        int lo = v & 31;
        int pos = base[lo] + atomicAdd(&cur[lo], 1);
        csr[pos] = (int)(v >> 5);
    }
}

// ---------- Layer-1 pull aggregation: lane = (edge-slot es, head h) ----------
// p for (edge es, head h) is computed by the SAME lane that gathers head h's
// 8 dims (16 B) of that edge's source row. No cross-lane ops in the loop.
__global__ __launch_bounds__(256) void k_agg1(const int* __restrict__ rowptr,
        const int* __restrict__ csr, const ushort* __restrict__ h1b,
        const float* __restrict__ als, const float* __restrict__ ald,
        const float* __restrict__ b1, float* __restrict__ hact, int N) {
    int n = blockIdx.x * 4 + (threadIdx.x >> 6);
    if (n >= N) return;
    int lane = threadIdx.x & 63;
    int es = lane >> 3;      // edge slot within 8-edge group
    int h = lane & 7;        // head; owns dims [8h, 8h+8)
    float aldh = ald[n * HEADS + h];
    int rs = rowptr[n], re = rowptr[n + 1];

    float a0 = 0.f, a1 = 0.f, a2 = 0.f, a3 = 0.f;
    float a4 = 0.f, a5 = 0.f, a6 = 0.f, a7 = 0.f;
    float den = 0.f;

    for (int jb = rs; jb < re; jb += 8) {
        int eidx = jb + es;
        bool valid = (eidx < re);
        int s = csr[valid ? eidx : rs];
        float e = als[s * HEADS + h] + aldh;
        e = fmaxf(e, NEG * e);              // leaky relu (exp2 domain, scale>0)
        float p = valid ? exp2f(e) : 0.f;
        uint4 u = *reinterpret_cast<const uint4*>(h1b + (long)s * HD + h * 8);
        // bf16 -> f32: lo = bits<<16, hi = bits&0xffff0000
        a0 += p * __uint_as_float(u.x << 16);
        a1 += p * __uint_as_float(u.x & 0xffff0000u);
        a2 += p * __uint_as_float(u.y << 16);
        a3 += p * __uint_as_float(u.y & 0xffff0000u);
        a4 += p * __uint_as_float(u.z << 16);
        a5 += p * __uint_as_float(u.z & 0xffff0000u);
        a6 += p * __uint_as_float(u.w << 16);
        a7 += p * __uint_as_float(u.w & 0xffff0000u);
        den += p;
    }
    // reduce over the 8 edge-slots (lanes with equal h: stride 8)
#pragma unroll
    for (int off = 8; off < 64; off <<= 1) {
        den += __shfl_xor(den, off);
        a0 += __shfl_xor(a0, off); a1 += __shfl_xor(a1, off);
        a2 += __shfl_xor(a2, off); a3 += __shfl_xor(a3, off);
        a4 += __shfl_xor(a4, off); a5 += __shfl_xor(a5, off);
        a6 += __shfl_xor(a6, off); a7 += __shfl_xor(a7, off);
    }
    float sel = (es < 4)
        ? ((es < 2) ? ((es == 0) ? a0 : a1) : ((es == 2) ? a2 : a3))
        : ((es < 6) ? ((es == 4) ? a4 : a5) : ((es == 6) ? a6 : a7));
    int d = h * 8 + es;
    float o = sel / (den + EPSV) + b1[d];
    o = (o > 0.f) ? o : __expf(o) - 1.f;   // ELU
    hact[(long)n * HD + d] = o;
}

// ---------- Layer-2 GEMM [N,64]x[64,3] + logits (wave per node) ----------
// h2p padded to float4 rows for single-load gathers in agg2.
__global__ __launch_bounds__(256) void k_gemm2(const float* __restrict__ hact,
        const float* __restrict__ W2, const float* __restrict__ as2,
        const float* __restrict__ ad2, float* __restrict__ h2p,
        float* __restrict__ als2, float* __restrict__ ald2, int N) {
    int n = blockIdx.x * 4 + (threadIdx.x >> 6);
    if (n >= N) return;
    int lane = threadIdx.x & 63;
    float hv = hact[(long)n * HD + lane];
    float p0 = hv * W2[lane * CLS + 0];
    float p1 = hv * W2[lane * CLS + 1];
    float p2 = hv * W2[lane * CLS + 2];
#pragma unroll
    for (int off = 32; off > 0; off >>= 1) {
        p0 += __shfl_down(p0, off);
        p1 += __shfl_down(p1, off);
        p2 += __shfl_down(p2, off);
    }
    if (lane == 0) {
        *reinterpret_cast<float4*>(h2p + (long)n * 4) = make_float4(p0, p1, p2, 0.f);
        als2[n] = (p0 * as2[0] + p1 * as2[1] + p2 * as2[2]) * LOG2E;
        ald2[n] = (p0 * ad2[0] + p1 * ad2[1] + p2 * ad2[2]) * LOG2E;
    }
}

// ---------- Layer-2 pull aggregation (no-max, exp2 domain) + log_softmax ----------
__global__ __launch_bounds__(256) void k_agg2(const int* __restrict__ rowptr,
        const int* __restrict__ csr, const float* __restrict__ h2p,
        const float* __restrict__ als2v, const float* __restrict__ ald2v,
        const float* __restrict__ b2, float* __restrict__ out, int N) {
    int n = blockIdx.x * 4 + (threadIdx.x >> 6);
    if (n >= N) return;
    int lane = threadIdx.x & 63;
    float aldv = ald2v[n];
    int rs = rowptr[n], re = rowptr[n + 1];
    float sum = 0.f, a0 = 0.f, a1 = 0.f, a2 = 0.f;
    for (int j = rs + lane; j < re; j += 64) {
        int s = csr[j];
        float e = als2v[s] + aldv;
        e = fmaxf(e, NEG * e);
        float p = exp2f(e);
        float4 hv = *reinterpret_cast<const float4*>(h2p + (long)s * 4);
        sum += p;
        a0 += p * hv.x;
        a1 += p * hv.y;
        a2 += p * hv.z;
    }
#pragma unroll
    for (int off = 1; off < 64; off <<= 1) {
        sum += __shfl_xor(sum, off);
        a0 += __shfl_xor(a0, off);
        a1 += __shfl_xor(a1, off);
        a2 += __shfl_xor(a2, off);
    }
    if (lane == 0) {
        float d = sum + EPSV;
        float v0 = a0 / d + b2[0], v1 = a1 / d + b2[1], v2 = a2 / d + b2[2];
        float mx = fmaxf(v0, fmaxf(v1, v2));
        float se = __expf(v0 - mx) + __expf(v1 - mx) + __expf(v2 - mx);
        float ls = mx + __logf(se);
        out[n * CLS + 0] = v0; out[n * CLS + 1] = v1; out[n * CLS + 2] = v2;
        long o2 = (long)N * CLS;
        out[o2 + n * CLS + 0] = v0 - ls;
        out[o2 + n * CLS + 1] = v1 - ls;
        out[o2 + n * CLS + 2] = v2 - ls;
    }
}

extern "C" void kernel_launch(void* const* d_in, const int* in_sizes, int n_in,
                              void* d_out, int out_size, void* d_ws, size_t ws_size,
                              hipStream_t stream) {
    const float* x   = (const float*)d_in[0];
    const void*  ei  = d_in[1];
    const float* W1  = (const float*)d_in[2];
    const float* as1 = (const float*)d_in[3];
    const float* ad1 = (const float*)d_in[4];
    const float* b1  = (const float*)d_in[5];
    const float* W2  = (const float*)d_in[6];
    const float* as2 = (const float*)d_in[7];
    const float* ad2 = (const float*)d_in[8];
    const float* b2  = (const float*)d_in[9];
    int N = in_sizes[0] / F_IN;
    int E = in_sizes[1] / 2;
    int tot = E + N;
    int nbkt = (N + 31) >> 5;

    char* w = (char*)d_ws;
    auto alloc = [&](size_t bytes) -> char* {
        char* p = w; w += (bytes + 255) & ~size_t(255); return p;
    };
    float*  h1     = (float*)alloc((size_t)N * HD * 4);   // dead after attlogits1
    ushort* h1b    = (ushort*)alloc((size_t)N * HD * 2);
    float*  hact   = (float*)alloc((size_t)N * HD * 4);
    float*  als1   = (float*)alloc((size_t)N * HEADS * 4);
    float*  ald1   = (float*)alloc((size_t)N * HEADS * 4);
    int*    rowptr = (int*)alloc((size_t)(N + 1) * 4);
    int*    deg    = (int*)alloc((size_t)N * 4);
    int nb = (N + SCB - 1) / SCB;
    int*    bsum   = (int*)alloc((size_t)nb * 4);
    int*    csr    = (int*)alloc((size_t)tot * 4);
    float*  h2p    = (float*)alloc((size_t)N * 4 * 4);
    float*  als2   = (float*)alloc((size_t)N * 4);
    float*  ald2   = (float*)alloc((size_t)N * 4);
    ushort* W1b2   = (ushort*)alloc((size_t)16 * 64 * 32 * 2);
    int*    flag   = (int*)alloc(256);

    // CSR-build scratch aliases h1 (dead after attlogits1, same-stream ordered).
    char* ov = (char*)h1;
    uint* pairs  = (uint*)ov;                      ov += ((size_t)tot * 4 + 255) & ~size_t(255);
    int*  ghist  = (int*)ov;                       ov += ((size_t)NBLK_H * nbkt * 4 + 255) & ~size_t(255);
    int*  colsum = (int*)ov;                       ov += ((size_t)nbkt * 4 + 255) & ~size_t(255);
    int*  boff   = (int*)ov;                       ov += ((size_t)(nbkt + 1) * 4 + 255) & ~size_t(255);

    k_detect<<<1, 1, 0, stream>>>((const int*)ei, flag);
    k_prepW<<<(16 * 64 * 32 + 255) / 256, 256, 0, stream>>>(W1, W1b2);
    k_gemm1<<<(N + 63) / 64, 256, 0, stream>>>(x, W1b2, h1, N);
    k_attlogits1<<<(N * HEADS + 255) / 256, 256, 0, stream>>>(h1, as1, ad1, als1, ald1, h1b, N);
    // ---- CSR build
    k_hist<<<NBLK_H, 256, 0, stream>>>(ei, E, N, nbkt, ghist, flag);
    k_bsum<<<(nbkt + 255) / 256, 256, 0, stream>>>(ghist, colsum, nbkt);
    k_bscan2<<<1, 256, 0, stream>>>(colsum, boff, nbkt);
    k_bapply<<<(nbkt + 255) / 256, 256, 0, stream>>>(ghist, boff, nbkt);
    k_scatter<<<NBLK_H, 256, 0, stream>>>(ei, E, N, nbkt, ghist, pairs, flag);
    k_deg2<<<nbkt, 256, 0, stream>>>(pairs, boff, deg, N);
    k_scan1<<<nb, SCB, 0, stream>>>(deg, rowptr, bsum, N);
    k_scan2<<<1, 1, 0, stream>>>(bsum, rowptr, nb, N);
    k_scan3<<<nb, SCB, 0, stream>>>(rowptr, bsum, N);
    k_fill2<<<nbkt, 256, 0, stream>>>(pairs, boff, rowptr, csr, N);
    // ---- aggregation / layer 2
    k_agg1<<<(N + 3) / 4, 256, 0, stream>>>(rowptr, csr, h1b, als1, ald1, b1, hact, N);
    k_gemm2<<<(N + 3) / 4, 256, 0, stream>>>(hact, W2, as2, ad2, h2p, als2, ald2, N);
    k_agg2<<<(N + 3) / 4, 256, 0, stream>>>(rowptr, csr, h2p, als2, ald2, b2, (float*)d_out, N);
}

// Round 9
// 388.886 us; speedup vs baseline: 1.1892x; 1.0554x over previous
//
#include <hip/hip_runtime.h>
#include <hip/hip_bf16.h>

// GAT 2-layer forward on MI355X.
// CSR-by-dst build via two-level counting sort + single-pass pull aggregation.
// gemm1: bf16 MFMA, double-buffered swizzled LDS staging, fused epilogue
// (attention logits + bf16 h1 emit straight from the output tile in LDS).
// agg1: lane=(edge-slot,head), lane-local p, 16-edge unroll (2 chains in flight).
// agg2: 2 nodes per wave.

#define F_IN 500
#define HEADS 8
#define HID 8
#define HD 64   // HEADS*HID
#define CLS 3
#define NEG 0.2f
#define EPSV 1e-16f
#define SCB 512
#define LOG2E 1.44269504088896340736f

#define NBLK_H 128     // blocks in hist/scatter passes
#define NBKT_MAX 3136  // >= ceil(N/32)

typedef __attribute__((ext_vector_type(8))) short short8v;   // 8 bf16
typedef __attribute__((ext_vector_type(4))) float f32x4;

__device__ inline short bfs(float v) {
    __hip_bfloat16 b = __float2bfloat16(v);
    return *(short*)&b;
}

// ---------- edge_index dtype detection (int32 vs int64 little-endian) ----------
__global__ void k_detect(const int* ei, int* flag) {
    int z = 0;
    for (int i = 1; i < 16; i += 2) z += (ei[i] == 0) ? 1 : 0;
    *flag = (z == 8) ? 1 : 0;
}

__device__ inline int ld_edge(const void* ei, long idx, int is64) {
    return is64 ? (int)((const long long*)ei)[idx] : ((const int*)ei)[idx];
}

// ---------- W1 -> bf16 slices W1b2[ks][c][kk], kk pre-swizzled ----------
__global__ void k_prepW(const float* __restrict__ W1, ushort* __restrict__ W1b2) {
    int i = blockIdx.x * 256 + threadIdx.x;
    if (i >= 16 * 64 * 32) return;
    int ks = i >> 11;
    int c = (i >> 5) & 63;
    int st = i & 31;
    int q = (st >> 3) ^ ((c >> 1) & 3);
    int k = ks * 32 + q * 8 + (st & 7);
    float v = (k < F_IN) ? W1[k * HD + c] : 0.f;
    __hip_bfloat16 b = __float2bfloat16(v);
    W1b2[i] = *(ushort*)&b;
}

// ---------- Layer-1 GEMM + fused logits epilogue ----------
__device__ __forceinline__ void g1_stage(const float* __restrict__ x,
        const ushort* __restrict__ W1b2, char* smem, int buf, int ks,
        int rowb, int N, int lane, int w) {
    const int k0 = ks * 32;
    {
        const ushort* srcB = W1b2 + ks * 2048 + (w * 64 + lane) * 8;
        char* dstB = smem + 16384 + buf * 4096 + w * 1024;
        __builtin_amdgcn_global_load_lds(
            (const __attribute__((address_space(1))) void*)srcB,
            (__attribute__((address_space(3))) void*)dstB, 16, 0, 0);
    }
#pragma unroll
    for (int i = 0; i < 2; ++i) {
        int vt = i * 256 + w * 64 + lane;
        int row = vt >> 3;
        int c = (vt & 7) ^ (row & 7);
        int ke = k0 + c * 4; if (ke > 496) ke = 496;
        int rowg = rowb + row; if (rowg >= N) rowg = N - 1;
        const float* srcA = x + (long)rowg * F_IN + ke;
        char* dstA = smem + buf * 8192 + i * 4096 + w * 1024;
        __builtin_amdgcn_global_load_lds(
            (const __attribute__((address_space(1))) void*)srcA,
            (__attribute__((address_space(3))) void*)dstA, 16, 0, 0);
    }
}

__global__ __launch_bounds__(256) void k_gemm1(const float* __restrict__ x,
        const ushort* __restrict__ W1b2,
        const float* __restrict__ asrc, const float* __restrict__ adst,
        float* __restrict__ als, float* __restrict__ ald,
        ushort* __restrict__ h1b, int N) {
    __shared__ char smem[24576];
    int t = threadIdx.x;
    int lane = t & 63;
    int w = t >> 6;
    int l16 = lane & 15, oct = lane >> 4;
    int rowb = blockIdx.x * 64;

    f32x4 acc0 = {0.f, 0.f, 0.f, 0.f};
    f32x4 acc1 = {0.f, 0.f, 0.f, 0.f};
    f32x4 acc2 = {0.f, 0.f, 0.f, 0.f};
    f32x4 acc3 = {0.f, 0.f, 0.f, 0.f};

    g1_stage(x, W1b2, smem, 0, 0, rowb, N, lane, w);
    __syncthreads();

    int rl = w * 16 + l16;
    int asw = l16 & 7;
    int bsw = (l16 >> 1) & 3;

    for (int ks = 0; ks < 16; ++ks) {
        int cur = ks & 1;
        if (ks < 15)
            g1_stage(x, W1b2, smem, cur ^ 1, ks + 1, rowb, N, lane, w);
        const char* Ab = smem + cur * 8192;
        const char* Bb = smem + 16384 + cur * 4096;
        float4 x0 = *reinterpret_cast<const float4*>(
            Ab + rl * 128 + ((2 * oct + 0) ^ asw) * 16);
        float4 x1 = *reinterpret_cast<const float4*>(
            Ab + rl * 128 + ((2 * oct + 1) ^ asw) * 16);
        short8v a;
        a[0] = bfs(x0.x); a[1] = bfs(x0.y); a[2] = bfs(x0.z); a[3] = bfs(x0.w);
        a[4] = bfs(x1.x); a[5] = bfs(x1.y); a[6] = bfs(x1.z); a[7] = bfs(x1.w);
        short8v b0 = *reinterpret_cast<const short8v*>(
            Bb + (0 * 16 + l16) * 64 + (oct ^ bsw) * 16);
        short8v b1 = *reinterpret_cast<const short8v*>(
            Bb + (1 * 16 + l16) * 64 + (oct ^ bsw) * 16);
        short8v b2 = *reinterpret_cast<const short8v*>(
            Bb + (2 * 16 + l16) * 64 + (oct ^ bsw) * 16);
        short8v b3 = *reinterpret_cast<const short8v*>(
            Bb + (3 * 16 + l16) * 64 + (oct ^ bsw) * 16);
        acc0 = __builtin_amdgcn_mfma_f32_16x16x32_bf16(a, b0, acc0, 0, 0, 0);
        acc1 = __builtin_amdgcn_mfma_f32_16x16x32_bf16(a, b1, acc1, 0, 0, 0);
        acc2 = __builtin_amdgcn_mfma_f32_16x16x32_bf16(a, b2, acc2, 0, 0, 0);
        acc3 = __builtin_amdgcn_mfma_f32_16x16x32_bf16(a, b3, acc3, 0, 0, 0);
        __syncthreads();
    }

    // ---- fused epilogue: park f32 tile in LDS, compute logits, emit bf16 h1
    float* fs = (float*)smem;   // 64 rows x 64 cols f32 = 16 KB
#pragma unroll
    for (int r = 0; r < 4; ++r) {
        int rl_ = w * 16 + oct * 4 + r;
        fs[rl_ * 64 + l16 +  0] = acc0[r];
        fs[rl_ * 64 + l16 + 16] = acc1[r];
        fs[rl_ * 64 + l16 + 32] = acc2[r];
        fs[rl_ * 64 + l16 + 48] = acc3[r];
    }
    __syncthreads();
#pragma unroll
    for (int j = t; j < 512; j += 256) {
        int row = j >> 3, h = j & 7;
        int gn = rowb + row;
        if (gn < N) {
            const float* hp = fs + row * 64 + h * 8;
            float4 v0 = *reinterpret_cast<const float4*>(hp);
            float4 v1 = *reinterpret_cast<const float4*>(hp + 4);
            const float* s = asrc + h * 8;
            const float* d = adst + h * 8;
            float s1 = v0.x * s[0] + v0.y * s[1] + v0.z * s[2] + v0.w * s[3]
                     + v1.x * s[4] + v1.y * s[5] + v1.z * s[6] + v1.w * s[7];
            float s2 = v0.x * d[0] + v0.y * d[1] + v0.z * d[2] + v0.w * d[3]
                     + v1.x * d[4] + v1.y * d[5] + v1.z * d[6] + v1.w * d[7];
            als[gn * 8 + h] = s1 * LOG2E;
            ald[gn * 8 + h] = s2 * LOG2E;
            ushort hb[8];
            hb[0] = (ushort)bfs(v0.x); hb[1] = (ushort)bfs(v0.y);
            hb[2] = (ushort)bfs(v0.z); hb[3] = (ushort)bfs(v0.w);
            hb[4] = (ushort)bfs(v1.x); hb[5] = (ushort)bfs(v1.y);
            hb[6] = (ushort)bfs(v1.z); hb[7] = (ushort)bfs(v1.w);
            *reinterpret_cast<uint4*>(h1b + (long)gn * HD + h * 8) =
                *reinterpret_cast<const uint4*>(hb);
        }
    }
}

// ================= CSR build: two-level counting sort =================

__global__ __launch_bounds__(256) void k_hist(const void* ei, int E, int N, int nbkt,
        int* __restrict__ ghist, const int* flag) {
    __shared__ int h[NBKT_MAX];
    int tot = E + N;
    int epb = (tot + NBLK_H - 1) / NBLK_H;
    int e0 = blockIdx.x * epb, e1 = min(tot, e0 + epb);
    for (int i = threadIdx.x; i < nbkt; i += 256) h[i] = 0;
    __syncthreads();
    int is64 = *flag;
    for (int e = e0 + threadIdx.x; e < e1; e += 256) {
        int dst = (e < E) ? ld_edge(ei, (long)E + e, is64) : (e - E);
        atomicAdd(&h[dst >> 5], 1);
    }
    __syncthreads();
    for (int i = threadIdx.x; i < nbkt; i += 256)
        ghist[blockIdx.x * nbkt + i] = h[i];
}

__global__ void k_bsum(const int* __restrict__ ghist, int* __restrict__ colsum, int nbkt) {
    int b = blockIdx.x * 256 + threadIdx.x;
    if (b >= nbkt) return;
    int s = 0;
    for (int i = 0; i < NBLK_H; i++) s += ghist[i * nbkt + b];
    colsum[b] = s;
}

__global__ __launch_bounds__(256) void k_bscan2(const int* __restrict__ colsum,
        int* __restrict__ boff, int nbkt) {
    __shared__ int part[256];
    int per = (nbkt + 255) / 256;
    int t = threadIdx.x;
    int lo = t * per, hi = min(nbkt, lo + per);
    int s = 0;
    for (int i = lo; i < hi; i++) s += colsum[i];
    part[t] = s;
    __syncthreads();
    for (int off = 1; off < 256; off <<= 1) {
        int v = (t >= off) ? part[t - off] : 0;
        __syncthreads();
        part[t] += v;
        __syncthreads();
    }
    int run = (t > 0) ? part[t - 1] : 0;
    for (int i = lo; i < hi; i++) { boff[i] = run; run += colsum[i]; }
    if (t == 255) boff[nbkt] = part[255];
}

__global__ void k_bapply(int* __restrict__ ghist, const int* __restrict__ boff, int nbkt) {
    int b = blockIdx.x * 256 + threadIdx.x;
    if (b >= nbkt) return;
    int run = boff[b];
    for (int i = 0; i < NBLK_H; i++) {
        int v = ghist[i * nbkt + b];
        ghist[i * nbkt + b] = run;
        run += v;
    }
}

__global__ __launch_bounds__(256) void k_scatter(const void* ei, int E, int N, int nbkt,
        const int* __restrict__ ghist, uint* __restrict__ pairs, const int* flag) {
    __shared__ int cur[NBKT_MAX];
    int tot = E + N;
    int epb = (tot + NBLK_H - 1) / NBLK_H;
    int e0 = blockIdx.x * epb, e1 = min(tot, e0 + epb);
    for (int i = threadIdx.x; i < nbkt; i += 256) cur[i] = ghist[blockIdx.x * nbkt + i];
    __syncthreads();
    int is64 = *flag;
    for (int e = e0 + threadIdx.x; e < e1; e += 256) {
        int src, dst;
        if (e < E) { src = ld_edge(ei, e, is64); dst = ld_edge(ei, (long)E + e, is64); }
        else { src = dst = e - E; }
        int pos = atomicAdd(&cur[dst >> 5], 1);
        pairs[pos] = ((uint)src << 5) | (uint)(dst & 31);
    }
}

__global__ __launch_bounds__(256) void k_deg2(const uint* __restrict__ pairs,
        const int* __restrict__ boff, int* __restrict__ deg, int N) {
    __shared__ int cnt[32];
    int b = blockIdx.x;
    if (threadIdx.x < 32) cnt[threadIdx.x] = 0;
    __syncthreads();
    int p0 = boff[b], p1 = boff[b + 1];
    for (int p = p0 + threadIdx.x; p < p1; p += 256)
        atomicAdd(&cnt[pairs[p] & 31], 1);
    __syncthreads();
    int n = b * 32 + threadIdx.x;
    if (threadIdx.x < 32 && n < N) deg[n] = cnt[threadIdx.x];
}

__global__ __launch_bounds__(SCB) void k_scan1(const int* deg, int* rowptr, int* bsum, int N) {
    __shared__ int s[SCB];
    int tid = threadIdx.x;
    int i = blockIdx.x * SCB + tid;
    int v = (i < N) ? deg[i] : 0;
    s[tid] = v;
    __syncthreads();
    for (int off = 1; off < SCB; off <<= 1) {
        int tv = (tid >= off) ? s[tid - off] : 0;
        __syncthreads();
        s[tid] += tv;
        __syncthreads();
    }
    if (i < N) rowptr[i] = s[tid] - v;
    if (tid == SCB - 1) bsum[blockIdx.x] = s[tid];
}

__global__ void k_scan2(int* bsum, int* rowptr, int nb, int N) {
    int run = 0;
    for (int i = 0; i < nb; i++) { int v = bsum[i]; bsum[i] = run; run += v; }
    rowptr[N] = run;
}

__global__ void k_scan3(int* rowptr, const int* bsum, int N) {
    int i = blockIdx.x * SCB + threadIdx.x;
    if (i < N) rowptr[i] += bsum[blockIdx.x];
}

__global__ __launch_bounds__(256) void k_fill2(const uint* __restrict__ pairs,
        const int* __restrict__ boff, const int* __restrict__ rowptr,
        int* __restrict__ csr, int N) {
    __shared__ int base[32];
    __shared__ int cur[32];
    int b = blockIdx.x;
    int n0 = b * 32;
    if (threadIdx.x < 32) {
        int n = n0 + threadIdx.x;
        base[threadIdx.x] = (n < N) ? rowptr[n] : 0;
        cur[threadIdx.x] = 0;
    }
    __syncthreads();
    int p0 = boff[b], p1 = boff[b + 1];
    for (int p = p0 + threadIdx.x; p < p1; p += 256) {
        uint v = pairs[p];
        int lo = v & 31;
        int pos = base[lo] + atomicAdd(&cur[lo], 1);
        csr[pos] = (int)(v >> 5);
    }
}

// ---------- Layer-1 pull aggregation: lane=(slot,head), 16-edge unroll ----------
__global__ __launch_bounds__(256) void k_agg1(const int* __restrict__ rowptr,
        const int* __restrict__ csr, const ushort* __restrict__ h1b,
        const float* __restrict__ als, const float* __restrict__ ald,
        const float* __restrict__ b1, float* __restrict__ hact, int N) {
    int n = blockIdx.x * 4 + (threadIdx.x >> 6);
    if (n >= N) return;
    int lane = threadIdx.x & 63;
    int es = lane >> 3;      // edge slot
    int h = lane & 7;        // head; owns dims [8h, 8h+8)
    float aldh = ald[n * HEADS + h];
    int rs = rowptr[n], re = rowptr[n + 1];

    float a0 = 0.f, a1 = 0.f, a2 = 0.f, a3 = 0.f;
    float a4 = 0.f, a5 = 0.f, a6 = 0.f, a7 = 0.f;
    float c0 = 0.f, c1 = 0.f, c2 = 0.f, c3 = 0.f;
    float c4 = 0.f, c5 = 0.f, c6 = 0.f, c7 = 0.f;
    float den = 0.f, den2 = 0.f;

    int jb = rs;
    for (; jb + 16 <= re; jb += 16) {           // unguarded, 2 chains in flight
        int sA = csr[jb + es];
        int sB = csr[jb + 8 + es];
        float eA = als[sA * HEADS + h] + aldh;
        float eB = als[sB * HEADS + h] + aldh;
        uint4 uA = *reinterpret_cast<const uint4*>(h1b + (long)sA * HD + h * 8);
        uint4 uB = *reinterpret_cast<const uint4*>(h1b + (long)sB * HD + h * 8);
        eA = fmaxf(eA, NEG * eA);
        eB = fmaxf(eB, NEG * eB);
        float pA = exp2f(eA);
        float pB = exp2f(eB);
        a0 += pA * __uint_as_float(uA.x << 16);
        a1 += pA * __uint_as_float(uA.x & 0xffff0000u);
        a2 += pA * __uint_as_float(uA.y << 16);
        a3 += pA * __uint_as_float(uA.y & 0xffff0000u);
        a4 += pA * __uint_as_float(uA.z << 16);
        a5 += pA * __uint_as_float(uA.z & 0xffff0000u);
        a6 += pA * __uint_as_float(uA.w << 16);
        a7 += pA * __uint_as_float(uA.w & 0xffff0000u);
        den += pA;
        c0 += pB * __uint_as_float(uB.x << 16);
        c1 += pB * __uint_as_float(uB.x & 0xffff0000u);
        c2 += pB * __uint_as_float(uB.y << 16);
        c3 += pB * __uint_as_float(uB.y & 0xffff0000u);
        c4 += pB * __uint_as_float(uB.z << 16);
        c5 += pB * __uint_as_float(uB.z & 0xffff0000u);
        c6 += pB * __uint_as_float(uB.w << 16);
        c7 += pB * __uint_as_float(uB.w & 0xffff0000u);
        den2 += pB;
    }
    for (; jb < re; jb += 8) {                   // guarded tail
        int eidx = jb + es;
        bool valid = (eidx < re);
        int s = csr[valid ? eidx : rs];
        float e = als[s * HEADS + h] + aldh;
        e = fmaxf(e, NEG * e);
        float p = valid ? exp2f(e) : 0.f;
        uint4 u = *reinterpret_cast<const uint4*>(h1b + (long)s * HD + h * 8);
        a0 += p * __uint_as_float(u.x << 16);
        a1 += p * __uint_as_float(u.x & 0xffff0000u);
        a2 += p * __uint_as_float(u.y << 16);
        a3 += p * __uint_as_float(u.y & 0xffff0000u);
        a4 += p * __uint_as_float(u.z << 16);
        a5 += p * __uint_as_float(u.z & 0xffff0000u);
        a6 += p * __uint_as_float(u.w << 16);
        a7 += p * __uint_as_float(u.w & 0xffff0000u);
        den += p;
    }
    a0 += c0; a1 += c1; a2 += c2; a3 += c3;
    a4 += c4; a5 += c5; a6 += c6; a7 += c7;
    den += den2;
#pragma unroll
    for (int off = 8; off < 64; off <<= 1) {
        den += __shfl_xor(den, off);
        a0 += __shfl_xor(a0, off); a1 += __shfl_xor(a1, off);
        a2 += __shfl_xor(a2, off); a3 += __shfl_xor(a3, off);
        a4 += __shfl_xor(a4, off); a5 += __shfl_xor(a5, off);
        a6 += __shfl_xor(a6, off); a7 += __shfl_xor(a7, off);
    }
    float sel = (es < 4)
        ? ((es < 2) ? ((es == 0) ? a0 : a1) : ((es == 2) ? a2 : a3))
        : ((es < 6) ? ((es == 4) ? a4 : a5) : ((es == 6) ? a6 : a7));
    int d = h * 8 + es;
    float o = sel / (den + EPSV) + b1[d];
    o = (o > 0.f) ? o : __expf(o) - 1.f;   // ELU
    hact[(long)n * HD + d] = o;
}

// ---------- Layer-2 GEMM [N,64]x[64,3] + logits (wave per node) ----------
__global__ __launch_bounds__(256) void k_gemm2(const float* __restrict__ hact,
        const float* __restrict__ W2, const float* __restrict__ as2,
        const float* __restrict__ ad2, float* __restrict__ h2p,
        float* __restrict__ als2, float* __restrict__ ald2, int N) {
    int n = blockIdx.x * 4 + (threadIdx.x >> 6);
    if (n >= N) return;
    int lane = threadIdx.x & 63;
    float hv = hact[(long)n * HD + lane];
    float p0 = hv * W2[lane * CLS + 0];
    float p1 = hv * W2[lane * CLS + 1];
    float p2 = hv * W2[lane * CLS + 2];
#pragma unroll
    for (int off = 32; off > 0; off >>= 1) {
        p0 += __shfl_down(p0, off);
        p1 += __shfl_down(p1, off);
        p2 += __shfl_down(p2, off);
    }
    if (lane == 0) {
        *reinterpret_cast<float4*>(h2p + (long)n * 4) = make_float4(p0, p1, p2, 0.f);
        als2[n] = (p0 * as2[0] + p1 * as2[1] + p2 * as2[2]) * LOG2E;
        ald2[n] = (p0 * ad2[0] + p1 * ad2[1] + p2 * ad2[2]) * LOG2E;
    }
}

// ---------- Layer-2 pull aggregation: 2 nodes/wave (32 lanes each) ----------
__global__ __launch_bounds__(256) void k_agg2(const int* __restrict__ rowptr,
        const int* __restrict__ csr, const float* __restrict__ h2p,
        const float* __restrict__ als2v, const float* __restrict__ ald2v,
        const float* __restrict__ b2, float* __restrict__ out, int N) {
    int n = blockIdx.x * 8 + (threadIdx.x >> 5);
    if (n >= N) return;
    int lane = threadIdx.x & 31;
    float aldv = ald2v[n];
    int rs = rowptr[n], re = rowptr[n + 1];
    float sum = 0.f, a0 = 0.f, a1 = 0.f, a2 = 0.f;
    for (int j = rs + lane; j < re; j += 32) {
        int s = csr[j];
        float e = als2v[s] + aldv;
        e = fmaxf(e, NEG * e);
        float p = exp2f(e);
        float4 hv = *reinterpret_cast<const float4*>(h2p + (long)s * 4);
        sum += p;
        a0 += p * hv.x;
        a1 += p * hv.y;
        a2 += p * hv.z;
    }
#pragma unroll
    for (int off = 1; off < 32; off <<= 1) {   // stays within 32-lane group
        sum += __shfl_xor(sum, off);
        a0 += __shfl_xor(a0, off);
        a1 += __shfl_xor(a1, off);
        a2 += __shfl_xor(a2, off);
    }
    if (lane == 0) {
        float d = sum + EPSV;
        float v0 = a0 / d + b2[0], v1 = a1 / d + b2[1], v2 = a2 / d + b2[2];
        float mx = fmaxf(v0, fmaxf(v1, v2));
        float se = __expf(v0 - mx) + __expf(v1 - mx) + __expf(v2 - mx);
        float ls = mx + __logf(se);
        out[n * CLS + 0] = v0; out[n * CLS + 1] = v1; out[n * CLS + 2] = v2;
        long o2 = (long)N * CLS;
        out[o2 + n * CLS + 0] = v0 - ls;
        out[o2 + n * CLS + 1] = v1 - ls;
        out[o2 + n * CLS + 2] = v2 - ls;
    }
}

extern "C" void kernel_launch(void* const* d_in, const int* in_sizes, int n_in,
                              void* d_out, int out_size, void* d_ws, size_t ws_size,
                              hipStream_t stream) {
    const float* x   = (const float*)d_in[0];
    const void*  ei  = d_in[1];
    const float* W1  = (const float*)d_in[2];
    const float* as1 = (const float*)d_in[3];
    const float* ad1 = (const float*)d_in[4];
    const float* b1  = (const float*)d_in[5];
    const float* W2  = (const float*)d_in[6];
    const float* as2 = (const float*)d_in[7];
    const float* ad2 = (const float*)d_in[8];
    const float* b2  = (const float*)d_in[9];
    int N = in_sizes[0] / F_IN;
    int E = in_sizes[1] / 2;
    int tot = E + N;
    int nbkt = (N + 31) >> 5;

    char* w = (char*)d_ws;
    auto alloc = [&](size_t bytes) -> char* {
        char* p = w; w += (bytes + 255) & ~size_t(255); return p;
    };
    ushort* h1b    = (ushort*)alloc((size_t)N * HD * 2);
    float*  hact   = (float*)alloc((size_t)N * HD * 4);
    float*  als1   = (float*)alloc((size_t)N * HEADS * 4);
    float*  ald1   = (float*)alloc((size_t)N * HEADS * 4);
    int*    rowptr = (int*)alloc((size_t)(N + 1) * 4);
    int*    deg    = (int*)alloc((size_t)N * 4);
    int nb = (N + SCB - 1) / SCB;
    int*    bsum   = (int*)alloc((size_t)nb * 4);
    int*    csr    = (int*)alloc((size_t)tot * 4);
    float*  h2p    = (float*)alloc((size_t)N * 4 * 4);
    float*  als2   = (float*)alloc((size_t)N * 4);
    float*  ald2   = (float*)alloc((size_t)N * 4);
    ushort* W1b2   = (ushort*)alloc((size_t)16 * 64 * 32 * 2);
    int*    flag   = (int*)alloc(256);
    uint*   pairs  = (uint*)alloc((size_t)tot * 4);
    int*    ghist  = (int*)alloc((size_t)NBLK_H * nbkt * 4);
    int*    colsum = (int*)alloc((size_t)nbkt * 4);
    int*    boff   = (int*)alloc((size_t)(nbkt + 1) * 4);

    k_detect<<<1, 1, 0, stream>>>((const int*)ei, flag);
    k_prepW<<<(16 * 64 * 32 + 255) / 256, 256, 0, stream>>>(W1, W1b2);
    k_gemm1<<<(N + 63) / 64, 256, 0, stream>>>(x, W1b2, as1, ad1, als1, ald1, h1b, N);
    // ---- CSR build
    k_hist<<<NBLK_H, 256, 0, stream>>>(ei, E, N, nbkt, ghist, flag);
    k_bsum<<<(nbkt + 255) / 256, 256, 0, stream>>>(ghist, colsum, nbkt);
    k_bscan2<<<1, 256, 0, stream>>>(colsum, boff, nbkt);
    k_bapply<<<(nbkt + 255) / 256, 256, 0, stream>>>(ghist, boff, nbkt);
    k_scatter<<<NBLK_H, 256, 0, stream>>>(ei, E, N, nbkt, ghist, pairs, flag);
    k_deg2<<<nbkt, 256, 0, stream>>>(pairs, boff, deg, N);
    k_scan1<<<nb, SCB, 0, stream>>>(deg, rowptr, bsum, N);
    k_scan2<<<1, 1, 0, stream>>>(bsum, rowptr, nb, N);
    k_scan3<<<nb, SCB, 0, stream>>>(rowptr, bsum, N);
    k_fill2<<<nbkt, 256, 0, stream>>>(pairs, boff, rowptr, csr, N);
    // ---- aggregation / layer 2
    k_agg1<<<(N + 3) / 4, 256, 0, stream>>>(rowptr, csr, h1b, als1, ald1, b1, hact, N);
    k_gemm2<<<(N + 3) / 4, 256, 0, stream>>>(hact, W2, as2, ad2, h2p, als2, ald2, N);
    k_agg2<<<(N + 7) / 8, 256, 0, stream>>>(rowptr, csr, h2p, als2, ald2, b2, (float*)d_out, N);
}

// Round 10
// 337.816 us; speedup vs baseline: 1.3690x; 1.1512x over previous
//
#include <hip/hip_runtime.h>
#include <hip/hip_bf16.h>

// GAT 2-layer forward on MI355X. 10-kernel pipeline:
// prepW(+detect), gemm1(MFMA+fused logits), hist, bsum, bscan2, bapply,
// scatter, fill3(deg+scan+fill fused), agg1(+gemm2 fused), agg2.

#define F_IN 500
#define HEADS 8
#define HID 8
#define HD 64   // HEADS*HID
#define CLS 3
#define NEG 0.2f
#define EPSV 1e-16f
#define LOG2E 1.44269504088896340736f

#define NBLK_H 128     // blocks in hist/scatter passes
#define NBKT_MAX 3136  // >= ceil(N/32)

typedef __attribute__((ext_vector_type(8))) short short8v;   // 8 bf16
typedef __attribute__((ext_vector_type(4))) float f32x4;

__device__ inline short bfs(float v) {
    __hip_bfloat16 b = __float2bfloat16(v);
    return *(short*)&b;
}

__device__ inline int ld_edge(const void* ei, long idx, int is64) {
    return is64 ? (int)((const long long*)ei)[idx] : ((const int*)ei)[idx];
}

// ---------- W1 -> bf16 slices (pre-swizzled) + edge dtype detect ----------
__global__ void k_prepW(const float* __restrict__ W1, ushort* __restrict__ W1b2,
                        const int* __restrict__ ei, int* __restrict__ flag) {
    if (blockIdx.x == 0 && threadIdx.x == 0) {
        int z = 0;
        for (int i = 1; i < 16; i += 2) z += (ei[i] == 0) ? 1 : 0;
        *flag = (z == 8) ? 1 : 0;
    }
    int i = blockIdx.x * 256 + threadIdx.x;
    if (i >= 16 * 64 * 32) return;
    int ks = i >> 11;
    int c = (i >> 5) & 63;
    int st = i & 31;
    int q = (st >> 3) ^ ((c >> 1) & 3);
    int k = ks * 32 + q * 8 + (st & 7);
    float v = (k < F_IN) ? W1[k * HD + c] : 0.f;
    __hip_bfloat16 b = __float2bfloat16(v);
    W1b2[i] = *(ushort*)&b;
}

// ---------- Layer-1 GEMM + fused logits epilogue ----------
__device__ __forceinline__ void g1_stage(const float* __restrict__ x,
        const ushort* __restrict__ W1b2, char* smem, int buf, int ks,
        int rowb, int N, int lane, int w) {
    const int k0 = ks * 32;
    {
        const ushort* srcB = W1b2 + ks * 2048 + (w * 64 + lane) * 8;
        char* dstB = smem + 16384 + buf * 4096 + w * 1024;
        __builtin_amdgcn_global_load_lds(
            (const __attribute__((address_space(1))) void*)srcB,
            (__attribute__((address_space(3))) void*)dstB, 16, 0, 0);
    }
#pragma unroll
    for (int i = 0; i < 2; ++i) {
        int vt = i * 256 + w * 64 + lane;
        int row = vt >> 3;
        int c = (vt & 7) ^ (row & 7);
        int ke = k0 + c * 4; if (ke > 496) ke = 496;
        int rowg = rowb + row; if (rowg >= N) rowg = N - 1;
        const float* srcA = x + (long)rowg * F_IN + ke;
        char* dstA = smem + buf * 8192 + i * 4096 + w * 1024;
        __builtin_amdgcn_global_load_lds(
            (const __attribute__((address_space(1))) void*)srcA,
            (__attribute__((address_space(3))) void*)dstA, 16, 0, 0);
    }
}

__global__ __launch_bounds__(256) void k_gemm1(const float* __restrict__ x,
        const ushort* __restrict__ W1b2,
        const float* __restrict__ asrc, const float* __restrict__ adst,
        float* __restrict__ als, float* __restrict__ ald,
        ushort* __restrict__ h1b, int N) {
    __shared__ char smem[24576];
    int t = threadIdx.x;
    int lane = t & 63;
    int w = t >> 6;
    int l16 = lane & 15, oct = lane >> 4;
    int rowb = blockIdx.x * 64;

    f32x4 acc0 = {0.f, 0.f, 0.f, 0.f};
    f32x4 acc1 = {0.f, 0.f, 0.f, 0.f};
    f32x4 acc2 = {0.f, 0.f, 0.f, 0.f};
    f32x4 acc3 = {0.f, 0.f, 0.f, 0.f};

    g1_stage(x, W1b2, smem, 0, 0, rowb, N, lane, w);
    __syncthreads();

    int rl = w * 16 + l16;
    int asw = l16 & 7;
    int bsw = (l16 >> 1) & 3;

    for (int ks = 0; ks < 16; ++ks) {
        int cur = ks & 1;
        if (ks < 15)
            g1_stage(x, W1b2, smem, cur ^ 1, ks + 1, rowb, N, lane, w);
        const char* Ab = smem + cur * 8192;
        const char* Bb = smem + 16384 + cur * 4096;
        float4 x0 = *reinterpret_cast<const float4*>(
            Ab + rl * 128 + ((2 * oct + 0) ^ asw) * 16);
        float4 x1 = *reinterpret_cast<const float4*>(
            Ab + rl * 128 + ((2 * oct + 1) ^ asw) * 16);
        short8v a;
        a[0] = bfs(x0.x); a[1] = bfs(x0.y); a[2] = bfs(x0.z); a[3] = bfs(x0.w);
        a[4] = bfs(x1.x); a[5] = bfs(x1.y); a[6] = bfs(x1.z); a[7] = bfs(x1.w);
        short8v b0 = *reinterpret_cast<const short8v*>(
            Bb + (0 * 16 + l16) * 64 + (oct ^ bsw) * 16);
        short8v b1 = *reinterpret_cast<const short8v*>(
            Bb + (1 * 16 + l16) * 64 + (oct ^ bsw) * 16);
        short8v b2 = *reinterpret_cast<const short8v*>(
            Bb + (2 * 16 + l16) * 64 + (oct ^ bsw) * 16);
        short8v b3 = *reinterpret_cast<const short8v*>(
            Bb + (3 * 16 + l16) * 64 + (oct ^ bsw) * 16);
        acc0 = __builtin_amdgcn_mfma_f32_16x16x32_bf16(a, b0, acc0, 0, 0, 0);
        acc1 = __builtin_amdgcn_mfma_f32_16x16x32_bf16(a, b1, acc1, 0, 0, 0);
        acc2 = __builtin_amdgcn_mfma_f32_16x16x32_bf16(a, b2, acc2, 0, 0, 0);
        acc3 = __builtin_amdgcn_mfma_f32_16x16x32_bf16(a, b3, acc3, 0, 0, 0);
        __syncthreads();
    }

    // ---- fused epilogue: park f32 tile in LDS, compute logits, emit bf16 h1
    float* fs = (float*)smem;   // 64 rows x 64 cols f32 = 16 KB
#pragma unroll
    for (int r = 0; r < 4; ++r) {
        int rl_ = w * 16 + oct * 4 + r;
        fs[rl_ * 64 + l16 +  0] = acc0[r];
        fs[rl_ * 64 + l16 + 16] = acc1[r];
        fs[rl_ * 64 + l16 + 32] = acc2[r];
        fs[rl_ * 64 + l16 + 48] = acc3[r];
    }
    __syncthreads();
#pragma unroll
    for (int j = t; j < 512; j += 256) {
        int row = j >> 3, h = j & 7;
        int gn = rowb + row;
        if (gn < N) {
            const float* hp = fs + row * 64 + h * 8;
            float4 v0 = *reinterpret_cast<const float4*>(hp);
            float4 v1 = *reinterpret_cast<const float4*>(hp + 4);
            const float* s = asrc + h * 8;
            const float* d = adst + h * 8;
            float s1 = v0.x * s[0] + v0.y * s[1] + v0.z * s[2] + v0.w * s[3]
                     + v1.x * s[4] + v1.y * s[5] + v1.z * s[6] + v1.w * s[7];
            float s2 = v0.x * d[0] + v0.y * d[1] + v0.z * d[2] + v0.w * d[3]
                     + v1.x * d[4] + v1.y * d[5] + v1.z * d[6] + v1.w * d[7];
            als[gn * 8 + h] = s1 * LOG2E;
            ald[gn * 8 + h] = s2 * LOG2E;
            ushort hb[8];
            hb[0] = (ushort)bfs(v0.x); hb[1] = (ushort)bfs(v0.y);
            hb[2] = (ushort)bfs(v0.z); hb[3] = (ushort)bfs(v0.w);
            hb[4] = (ushort)bfs(v1.x); hb[5] = (ushort)bfs(v1.y);
            hb[6] = (ushort)bfs(v1.z); hb[7] = (ushort)bfs(v1.w);
            *reinterpret_cast<uint4*>(h1b + (long)gn * HD + h * 8) =
                *reinterpret_cast<const uint4*>(hb);
        }
    }
}

// ================= CSR build =================

__global__ __launch_bounds__(256) void k_hist(const void* ei, int E, int N, int nbkt,
        int* __restrict__ ghist, const int* flag) {
    __shared__ int h[NBKT_MAX];
    int tot = E + N;
    int epb = (tot + NBLK_H - 1) / NBLK_H;
    int e0 = blockIdx.x * epb, e1 = min(tot, e0 + epb);
    for (int i = threadIdx.x; i < nbkt; i += 256) h[i] = 0;
    __syncthreads();
    int is64 = *flag;
    for (int e = e0 + threadIdx.x; e < e1; e += 256) {
        int dst = (e < E) ? ld_edge(ei, (long)E + e, is64) : (e - E);
        atomicAdd(&h[dst >> 5], 1);
    }
    __syncthreads();
    for (int i = threadIdx.x; i < nbkt; i += 256)
        ghist[blockIdx.x * nbkt + i] = h[i];
}

__global__ void k_bsum(const int* __restrict__ ghist, int* __restrict__ colsum, int nbkt) {
    int b = blockIdx.x * 256 + threadIdx.x;
    if (b >= nbkt) return;
    int s = 0;
    for (int i = 0; i < NBLK_H; i++) s += ghist[i * nbkt + b];
    colsum[b] = s;
}

__global__ __launch_bounds__(256) void k_bscan2(const int* __restrict__ colsum,
        int* __restrict__ boff, int nbkt) {
    __shared__ int part[256];
    int per = (nbkt + 255) / 256;
    int t = threadIdx.x;
    int lo = t * per, hi = min(nbkt, lo + per);
    int s = 0;
    for (int i = lo; i < hi; i++) s += colsum[i];
    part[t] = s;
    __syncthreads();
    for (int off = 1; off < 256; off <<= 1) {
        int v = (t >= off) ? part[t - off] : 0;
        __syncthreads();
        part[t] += v;
        __syncthreads();
    }
    int run = (t > 0) ? part[t - 1] : 0;
    for (int i = lo; i < hi; i++) { boff[i] = run; run += colsum[i]; }
    if (t == 255) boff[nbkt] = part[255];
}

__global__ void k_bapply(int* __restrict__ ghist, const int* __restrict__ boff, int nbkt) {
    int b = blockIdx.x * 256 + threadIdx.x;
    if (b >= nbkt) return;
    int run = boff[b];
    for (int i = 0; i < NBLK_H; i++) {
        int v = ghist[i * nbkt + b];
        ghist[i * nbkt + b] = run;
        run += v;
    }
}

__global__ __launch_bounds__(256) void k_scatter(const void* ei, int E, int N, int nbkt,
        const int* __restrict__ ghist, uint* __restrict__ pairs, const int* flag) {
    __shared__ int cur[NBKT_MAX];
    int tot = E + N;
    int epb = (tot + NBLK_H - 1) / NBLK_H;
    int e0 = blockIdx.x * epb, e1 = min(tot, e0 + epb);
    for (int i = threadIdx.x; i < nbkt; i += 256) cur[i] = ghist[blockIdx.x * nbkt + i];
    __syncthreads();
    int is64 = *flag;
    for (int e = e0 + threadIdx.x; e < e1; e += 256) {
        int src, dst;
        if (e < E) { src = ld_edge(ei, e, is64); dst = ld_edge(ei, (long)E + e, is64); }
        else { src = dst = e - E; }
        int pos = atomicAdd(&cur[dst >> 5], 1);
        pairs[pos] = ((uint)src << 5) | (uint)(dst & 31);
    }
}

// ---------- fused deg + scan + fill: one block per 32-node bucket ----------
__global__ __launch_bounds__(256) void k_fill3(const uint* __restrict__ pairs,
        const int* __restrict__ boff, int* __restrict__ rowptr,
        int* __restrict__ csr, int N, int nbkt) {
    __shared__ int cnt[32];
    __shared__ int base[32];
    __shared__ int cur[32];
    int b = blockIdx.x;
    int t = threadIdx.x;
    if (t < 32) { cnt[t] = 0; cur[t] = 0; }
    __syncthreads();
    int p0 = boff[b], p1 = boff[b + 1];
    for (int p = p0 + t; p < p1; p += 256)
        atomicAdd(&cnt[pairs[p] & 31], 1);
    __syncthreads();
    if (t < 32) {
        int pre = 0;
#pragma unroll
        for (int i = 0; i < 32; i++) pre += (i < t) ? cnt[i] : 0;
        base[t] = p0 + pre;
        int n = b * 32 + t;
        if (n < N) rowptr[n] = base[t];
    }
    if (b == 0 && t == 0) rowptr[N] = boff[nbkt];
    __syncthreads();
    for (int p = p0 + t; p < p1; p += 256) {
        uint v = pairs[p];
        int lo = v & 31;
        int pos = base[lo] + atomicAdd(&cur[lo], 1);
        csr[pos] = (int)(v >> 5);
    }
}

// ---------- Layer-1 aggregation + fused layer-2 projection ----------
// lane=(edge-slot es, head h); lane-local p; 16-edge unroll; after the
// per-head reduce, apply bias+ELU, then 3 full-wave reduces give the
// layer-2 logits (gemm2 fused). hact never materialized.
__global__ __launch_bounds__(256) void k_agg1(const int* __restrict__ rowptr,
        const int* __restrict__ csr, const ushort* __restrict__ h1b,
        const float* __restrict__ als, const float* __restrict__ ald,
        const float* __restrict__ b1, const float* __restrict__ W2,
        const float* __restrict__ as2, const float* __restrict__ ad2,
        float* __restrict__ h2p, float* __restrict__ als2,
        float* __restrict__ ald2, int N) {
    int n = blockIdx.x * 4 + (threadIdx.x >> 6);
    if (n >= N) return;
    int lane = threadIdx.x & 63;
    int es = lane >> 3;      // edge slot
    int h = lane & 7;        // head; owns dims [8h, 8h+8)
    float aldh = ald[n * HEADS + h];
    int rs = rowptr[n], re = rowptr[n + 1];

    float a0 = 0.f, a1 = 0.f, a2 = 0.f, a3 = 0.f;
    float a4 = 0.f, a5 = 0.f, a6 = 0.f, a7 = 0.f;
    float c0 = 0.f, c1 = 0.f, c2 = 0.f, c3 = 0.f;
    float c4 = 0.f, c5 = 0.f, c6 = 0.f, c7 = 0.f;
    float den = 0.f, den2 = 0.f;

    int jb = rs;
    for (; jb + 16 <= re; jb += 16) {           // unguarded, 2 chains in flight
        int sA = csr[jb + es];
        int sB = csr[jb + 8 + es];
        float eA = als[sA * HEADS + h] + aldh;
        float eB = als[sB * HEADS + h] + aldh;
        uint4 uA = *reinterpret_cast<const uint4*>(h1b + (long)sA * HD + h * 8);
        uint4 uB = *reinterpret_cast<const uint4*>(h1b + (long)sB * HD + h * 8);
        eA = fmaxf(eA, NEG * eA);
        eB = fmaxf(eB, NEG * eB);
        float pA = exp2f(eA);
        float pB = exp2f(eB);
        a0 += pA * __uint_as_float(uA.x << 16);
        a1 += pA * __uint_as_float(uA.x & 0xffff0000u);
        a2 += pA * __uint_as_float(uA.y << 16);
        a3 += pA * __uint_as_float(uA.y & 0xffff0000u);
        a4 += pA * __uint_as_float(uA.z << 16);
        a5 += pA * __uint_as_float(uA.z & 0xffff0000u);
        a6 += pA * __uint_as_float(uA.w << 16);
        a7 += pA * __uint_as_float(uA.w & 0xffff0000u);
        den += pA;
        c0 += pB * __uint_as_float(uB.x << 16);
        c1 += pB * __uint_as_float(uB.x & 0xffff0000u);
        c2 += pB * __uint_as_float(uB.y << 16);
        c3 += pB * __uint_as_float(uB.y & 0xffff0000u);
        c4 += pB * __uint_as_float(uB.z << 16);
        c5 += pB * __uint_as_float(uB.z & 0xffff0000u);
        c6 += pB * __uint_as_float(uB.w << 16);
        c7 += pB * __uint_as_float(uB.w & 0xffff0000u);
        den2 += pB;
    }
    for (; jb < re; jb += 8) {                   // guarded tail
        int eidx = jb + es;
        bool valid = (eidx < re);
        int s = csr[valid ? eidx : rs];
        float e = als[s * HEADS + h] + aldh;
        e = fmaxf(e, NEG * e);
        float p = valid ? exp2f(e) : 0.f;
        uint4 u = *reinterpret_cast<const uint4*>(h1b + (long)s * HD + h * 8);
        a0 += p * __uint_as_float(u.x << 16);
        a1 += p * __uint_as_float(u.x & 0xffff0000u);
        a2 += p * __uint_as_float(u.y << 16);
        a3 += p * __uint_as_float(u.y & 0xffff0000u);
        a4 += p * __uint_as_float(u.z << 16);
        a5 += p * __uint_as_float(u.z & 0xffff0000u);
        a6 += p * __uint_as_float(u.w << 16);
        a7 += p * __uint_as_float(u.w & 0xffff0000u);
        den += p;
    }
    a0 += c0; a1 += c1; a2 += c2; a3 += c3;
    a4 += c4; a5 += c5; a6 += c6; a7 += c7;
    den += den2;
#pragma unroll
    for (int off = 8; off < 64; off <<= 1) {
        den += __shfl_xor(den, off);
        a0 += __shfl_xor(a0, off); a1 += __shfl_xor(a1, off);
        a2 += __shfl_xor(a2, off); a3 += __shfl_xor(a3, off);
        a4 += __shfl_xor(a4, off); a5 += __shfl_xor(a5, off);
        a6 += __shfl_xor(a6, off); a7 += __shfl_xor(a7, off);
    }
    float sel = (es < 4)
        ? ((es < 2) ? ((es == 0) ? a0 : a1) : ((es == 2) ? a2 : a3))
        : ((es < 6) ? ((es == 4) ? a4 : a5) : ((es == 6) ? a6 : a7));
    int d = h * 8 + es;
    float o = sel / (den + EPSV) + b1[d];
    o = (o > 0.f) ? o : __expf(o) - 1.f;   // ELU
    // ---- fused gemm2: p_c = sum_d o_d * W2[d][c]
    float p0 = o * W2[d * CLS + 0];
    float p1 = o * W2[d * CLS + 1];
    float p2 = o * W2[d * CLS + 2];
#pragma unroll
    for (int off = 1; off < 64; off <<= 1) {
        p0 += __shfl_xor(p0, off);
        p1 += __shfl_xor(p1, off);
        p2 += __shfl_xor(p2, off);
    }
    if (lane == 0) {
        *reinterpret_cast<float4*>(h2p + (long)n * 4) = make_float4(p0, p1, p2, 0.f);
        als2[n] = (p0 * as2[0] + p1 * as2[1] + p2 * as2[2]) * LOG2E;
        ald2[n] = (p0 * ad2[0] + p1 * ad2[1] + p2 * ad2[2]) * LOG2E;
    }
}

// ---------- Layer-2 pull aggregation: 2 nodes/wave (32 lanes each) ----------
__global__ __launch_bounds__(256) void k_agg2(const int* __restrict__ rowptr,
        const int* __restrict__ csr, const float* __restrict__ h2p,
        const float* __restrict__ als2v, const float* __restrict__ ald2v,
        const float* __restrict__ b2, float* __restrict__ out, int N) {
    int n = blockIdx.x * 8 + (threadIdx.x >> 5);
    if (n >= N) return;
    int lane = threadIdx.x & 31;
    float aldv = ald2v[n];
    int rs = rowptr[n], re = rowptr[n + 1];
    float sum = 0.f, a0 = 0.f, a1 = 0.f, a2 = 0.f;
    for (int j = rs + lane; j < re; j += 32) {
        int s = csr[j];
        float e = als2v[s] + aldv;
        e = fmaxf(e, NEG * e);
        float p = exp2f(e);
        float4 hv = *reinterpret_cast<const float4*>(h2p + (long)s * 4);
        sum += p;
        a0 += p * hv.x;
        a1 += p * hv.y;
        a2 += p * hv.z;
    }
#pragma unroll
    for (int off = 1; off < 32; off <<= 1) {   // stays within 32-lane group
        sum += __shfl_xor(sum, off);
        a0 += __shfl_xor(a0, off);
        a1 += __shfl_xor(a1, off);
        a2 += __shfl_xor(a2, off);
    }
    if (lane == 0) {
        float d = sum + EPSV;
        float v0 = a0 / d + b2[0], v1 = a1 / d + b2[1], v2 = a2 / d + b2[2];
        float mx = fmaxf(v0, fmaxf(v1, v2));
        float se = __expf(v0 - mx) + __expf(v1 - mx) + __expf(v2 - mx);
        float ls = mx + __logf(se);
        out[n * CLS + 0] = v0; out[n * CLS + 1] = v1; out[n * CLS + 2] = v2;
        long o2 = (long)N * CLS;
        out[o2 + n * CLS + 0] = v0 - ls;
        out[o2 + n * CLS + 1] = v1 - ls;
        out[o2 + n * CLS + 2] = v2 - ls;
    }
}

extern "C" void kernel_launch(void* const* d_in, const int* in_sizes, int n_in,
                              void* d_out, int out_size, void* d_ws, size_t ws_size,
                              hipStream_t stream) {
    const float* x   = (const float*)d_in[0];
    const void*  ei  = d_in[1];
    const float* W1  = (const float*)d_in[2];
    const float* as1 = (const float*)d_in[3];
    const float* ad1 = (const float*)d_in[4];
    const float* b1  = (const float*)d_in[5];
    const float* W2  = (const float*)d_in[6];
    const float* as2 = (const float*)d_in[7];
    const float* ad2 = (const float*)d_in[8];
    const float* b2  = (const float*)d_in[9];
    int N = in_sizes[0] / F_IN;
    int E = in_sizes[1] / 2;
    int tot = E + N;
    int nbkt = (N + 31) >> 5;

    char* w = (char*)d_ws;
    auto alloc = [&](size_t bytes) -> char* {
        char* p = w; w += (bytes + 255) & ~size_t(255); return p;
    };
    ushort* h1b    = (ushort*)alloc((size_t)N * HD * 2);
    float*  als1   = (float*)alloc((size_t)N * HEADS * 4);
    float*  ald1   = (float*)alloc((size_t)N * HEADS * 4);
    int*    rowptr = (int*)alloc((size_t)(N + 1) * 4);
    int*    csr    = (int*)alloc((size_t)tot * 4);
    float*  h2p    = (float*)alloc((size_t)N * 4 * 4);
    float*  als2   = (float*)alloc((size_t)N * 4);
    float*  ald2   = (float*)alloc((size_t)N * 4);
    ushort* W1b2   = (ushort*)alloc((size_t)16 * 64 * 32 * 2);
    int*    flag   = (int*)alloc(256);
    uint*   pairs  = (uint*)alloc((size_t)tot * 4);
    int*    ghist  = (int*)alloc((size_t)NBLK_H * nbkt * 4);
    int*    colsum = (int*)alloc((size_t)nbkt * 4);
    int*    boff   = (int*)alloc((size_t)(nbkt + 1) * 4);

    k_prepW<<<(16 * 64 * 32 + 255) / 256, 256, 0, stream>>>(W1, W1b2, (const int*)ei, flag);
    k_gemm1<<<(N + 63) / 64, 256, 0, stream>>>(x, W1b2, as1, ad1, als1, ald1, h1b, N);
    // ---- CSR build
    k_hist<<<NBLK_H, 256, 0, stream>>>(ei, E, N, nbkt, ghist, flag);
    k_bsum<<<(nbkt + 255) / 256, 256, 0, stream>>>(ghist, colsum, nbkt);
    k_bscan2<<<1, 256, 0, stream>>>(colsum, boff, nbkt);
    k_bapply<<<(nbkt + 255) / 256, 256, 0, stream>>>(ghist, boff, nbkt);
    k_scatter<<<NBLK_H, 256, 0, stream>>>(ei, E, N, nbkt, ghist, pairs, flag);
    k_fill3<<<nbkt, 256, 0, stream>>>(pairs, boff, rowptr, csr, N, nbkt);
    // ---- aggregation (layer-2 projection fused) / layer-2 aggregation
    k_agg1<<<(N + 3) / 4, 256, 0, stream>>>(rowptr, csr, h1b, als1, ald1, b1,
                                            W2, as2, ad2, h2p, als2, ald2, N);
    k_agg2<<<(N + 7) / 8, 256, 0, stream>>>(rowptr, csr, h2p, als2, ald2, b2,
                                            (float*)d_out, N);
}

// Round 11
// 306.702 us; speedup vs baseline: 1.5079x; 1.1014x over previous
//
#include <hip/hip_runtime.h>
#include <hip/hip_bf16.h>

// GAT 2-layer forward on MI355X. 9-kernel pipeline:
// prepW(+detect), fatA(gemm1 MFMA+logits ∥ edge-histogram), bsum, bscan2,
// bapply, scatter, fill3(deg+scan+fill), agg1(+gemm2 fused), agg2.

#define F_IN 500
#define HEADS 8
#define HID 8
#define HD 64
#define CLS 3
#define NEG 0.2f
#define EPSV 1e-16f
#define LOG2E 1.44269504088896340736f

#define NBLK_H 256     // blocks in hist/scatter passes
#define NBKT_MAX 3136  // >= ceil(N/32)

typedef __attribute__((ext_vector_type(8))) short short8v;   // 8 bf16
typedef __attribute__((ext_vector_type(4))) float f32x4;

__device__ inline short bfs(float v) {
    __hip_bfloat16 b = __float2bfloat16(v);
    return *(short*)&b;
}

__device__ inline int ld_edge(const void* ei, long idx, int is64) {
    return is64 ? (int)((const long long*)ei)[idx] : ((const int*)ei)[idx];
}

// ---------- W1 -> bf16 slices (pre-swizzled) + edge dtype detect ----------
__global__ void k_prepW(const float* __restrict__ W1, ushort* __restrict__ W1b2,
                        const int* __restrict__ ei, int* __restrict__ flag) {
    if (blockIdx.x == 0 && threadIdx.x == 0) {
        int z = 0;
        for (int i = 1; i < 16; i += 2) z += (ei[i] == 0) ? 1 : 0;
        *flag = (z == 8) ? 1 : 0;
    }
    int i = blockIdx.x * 256 + threadIdx.x;
    if (i >= 16 * 64 * 32) return;
    int ks = i >> 11;
    int c = (i >> 5) & 63;
    int st = i & 31;
    int q = (st >> 3) ^ ((c >> 1) & 3);
    int k = ks * 32 + q * 8 + (st & 7);
    float v = (k < F_IN) ? W1[k * HD + c] : 0.f;
    __hip_bfloat16 b = __float2bfloat16(v);
    W1b2[i] = *(ushort*)&b;
}

// ---------- fatA: gemm1 (blocks < gB) || edge histogram (last NBLK_H) ----------
__device__ __forceinline__ void g1_stage(const float* __restrict__ x,
        const ushort* __restrict__ W1b2, char* smem, int buf, int ks,
        int rowb, int N, int lane, int w) {
    const int k0 = ks * 32;
    {
        const ushort* srcB = W1b2 + ks * 2048 + (w * 64 + lane) * 8;
        char* dstB = smem + 16384 + buf * 4096 + w * 1024;
        __builtin_amdgcn_global_load_lds(
            (const __attribute__((address_space(1))) void*)srcB,
            (__attribute__((address_space(3))) void*)dstB, 16, 0, 0);
    }
#pragma unroll
    for (int i = 0; i < 2; ++i) {
        int vt = i * 256 + w * 64 + lane;
        int row = vt >> 3;
        int c = (vt & 7) ^ (row & 7);
        int ke = k0 + c * 4; if (ke > 496) ke = 496;
        int rowg = rowb + row; if (rowg >= N) rowg = N - 1;
        const float* srcA = x + (long)rowg * F_IN + ke;
        char* dstA = smem + buf * 8192 + i * 4096 + w * 1024;
        __builtin_amdgcn_global_load_lds(
            (const __attribute__((address_space(1))) void*)srcA,
            (__attribute__((address_space(3))) void*)dstA, 16, 0, 0);
    }
}

__global__ __launch_bounds__(256) void k_fatA(const float* __restrict__ x,
        const ushort* __restrict__ W1b2,
        const float* __restrict__ asrc, const float* __restrict__ adst,
        float* __restrict__ als, float* __restrict__ ald,
        ushort* __restrict__ h1b, int N,
        const void* ei, int E, int nbkt, int* __restrict__ ghist,
        const int* __restrict__ flag) {
    __shared__ char smem[24576];
    int gB = (N + 63) >> 6;
    int t = threadIdx.x;

    if ((int)blockIdx.x >= gB) {
        // ================= histogram branch =================
        int hb = blockIdx.x - gB;
        int* h = (int*)smem;
        int tot = E + N;
        int epb = (tot + NBLK_H - 1) / NBLK_H;
        int e0 = hb * epb, e1 = min(tot, e0 + epb);
        for (int i = t; i < nbkt; i += 256) h[i] = 0;
        __syncthreads();
        int is64 = *flag;
        for (int e = e0 + t; e < e1; e += 256) {
            int dst = (e < E) ? ld_edge(ei, (long)E + e, is64) : (e - E);
            atomicAdd(&h[dst >> 5], 1);
        }
        __syncthreads();
        for (int i = t; i < nbkt; i += 256)
            ghist[hb * nbkt + i] = h[i];
        return;
    }

    // ================= gemm1 branch =================
    int lane = t & 63;
    int w = t >> 6;
    int l16 = lane & 15, oct = lane >> 4;
    int rowb = blockIdx.x * 64;

    f32x4 acc0 = {0.f, 0.f, 0.f, 0.f};
    f32x4 acc1 = {0.f, 0.f, 0.f, 0.f};
    f32x4 acc2 = {0.f, 0.f, 0.f, 0.f};
    f32x4 acc3 = {0.f, 0.f, 0.f, 0.f};

    g1_stage(x, W1b2, smem, 0, 0, rowb, N, lane, w);
    __syncthreads();

    int rl = w * 16 + l16;
    int asw = l16 & 7;
    int bsw = (l16 >> 1) & 3;

    for (int ks = 0; ks < 16; ++ks) {
        int cur = ks & 1;
        if (ks < 15)
            g1_stage(x, W1b2, smem, cur ^ 1, ks + 1, rowb, N, lane, w);
        const char* Ab = smem + cur * 8192;
        const char* Bb = smem + 16384 + cur * 4096;
        float4 x0 = *reinterpret_cast<const float4*>(
            Ab + rl * 128 + ((2 * oct + 0) ^ asw) * 16);
        float4 x1 = *reinterpret_cast<const float4*>(
            Ab + rl * 128 + ((2 * oct + 1) ^ asw) * 16);
        short8v a;
        a[0] = bfs(x0.x); a[1] = bfs(x0.y); a[2] = bfs(x0.z); a[3] = bfs(x0.w);
        a[4] = bfs(x1.x); a[5] = bfs(x1.y); a[6] = bfs(x1.z); a[7] = bfs(x1.w);
        short8v b0 = *reinterpret_cast<const short8v*>(
            Bb + (0 * 16 + l16) * 64 + (oct ^ bsw) * 16);
        short8v b1 = *reinterpret_cast<const short8v*>(
            Bb + (1 * 16 + l16) * 64 + (oct ^ bsw) * 16);
        short8v b2 = *reinterpret_cast<const short8v*>(
            Bb + (2 * 16 + l16) * 64 + (oct ^ bsw) * 16);
        short8v b3 = *reinterpret_cast<const short8v*>(
            Bb + (3 * 16 + l16) * 64 + (oct ^ bsw) * 16);
        acc0 = __builtin_amdgcn_mfma_f32_16x16x32_bf16(a, b0, acc0, 0, 0, 0);
        acc1 = __builtin_amdgcn_mfma_f32_16x16x32_bf16(a, b1, acc1, 0, 0, 0);
        acc2 = __builtin_amdgcn_mfma_f32_16x16x32_bf16(a, b2, acc2, 0, 0, 0);
        acc3 = __builtin_amdgcn_mfma_f32_16x16x32_bf16(a, b3, acc3, 0, 0, 0);
        __syncthreads();
    }

    float* fs = (float*)smem;   // 64 x 64 f32 = 16 KB
#pragma unroll
    for (int r = 0; r < 4; ++r) {
        int rl_ = w * 16 + oct * 4 + r;
        fs[rl_ * 64 + l16 +  0] = acc0[r];
        fs[rl_ * 64 + l16 + 16] = acc1[r];
        fs[rl_ * 64 + l16 + 32] = acc2[r];
        fs[rl_ * 64 + l16 + 48] = acc3[r];
    }
    __syncthreads();
#pragma unroll
    for (int j = t; j < 512; j += 256) {
        int row = j >> 3, h = j & 7;
        int gn = rowb + row;
        if (gn < N) {
            const float* hp = fs + row * 64 + h * 8;
            float4 v0 = *reinterpret_cast<const float4*>(hp);
            float4 v1 = *reinterpret_cast<const float4*>(hp + 4);
            const float* s = asrc + h * 8;
            const float* d = adst + h * 8;
            float s1 = v0.x * s[0] + v0.y * s[1] + v0.z * s[2] + v0.w * s[3]
                     + v1.x * s[4] + v1.y * s[5] + v1.z * s[6] + v1.w * s[7];
            float s2 = v0.x * d[0] + v0.y * d[1] + v0.z * d[2] + v0.w * d[3]
                     + v1.x * d[4] + v1.y * d[5] + v1.z * d[6] + v1.w * d[7];
            als[gn * 8 + h] = s1 * LOG2E;
            ald[gn * 8 + h] = s2 * LOG2E;
            ushort hb[8];
            hb[0] = (ushort)bfs(v0.x); hb[1] = (ushort)bfs(v0.y);
            hb[2] = (ushort)bfs(v0.z); hb[3] = (ushort)bfs(v0.w);
            hb[4] = (ushort)bfs(v1.x); hb[5] = (ushort)bfs(v1.y);
            hb[6] = (ushort)bfs(v1.z); hb[7] = (ushort)bfs(v1.w);
            *reinterpret_cast<uint4*>(h1b + (long)gn * HD + h * 8) =
                *reinterpret_cast<const uint4*>(hb);
        }
    }
}

// ================= CSR build tail =================

__global__ void k_bsum(const int* __restrict__ ghist, int* __restrict__ colsum, int nbkt) {
    int b = blockIdx.x * 256 + threadIdx.x;
    if (b >= nbkt) return;
    int s = 0;
    for (int i = 0; i < NBLK_H; i++) s += ghist[i * nbkt + b];
    colsum[b] = s;
}

__global__ __launch_bounds__(256) void k_bscan2(const int* __restrict__ colsum,
        int* __restrict__ boff, int nbkt) {
    __shared__ int part[256];
    int per = (nbkt + 255) / 256;
    int t = threadIdx.x;
    int lo = t * per, hi = min(nbkt, lo + per);
    int s = 0;
    for (int i = lo; i < hi; i++) s += colsum[i];
    part[t] = s;
    __syncthreads();
    for (int off = 1; off < 256; off <<= 1) {
        int v = (t >= off) ? part[t - off] : 0;
        __syncthreads();
        part[t] += v;
        __syncthreads();
    }
    int run = (t > 0) ? part[t - 1] : 0;
    for (int i = lo; i < hi; i++) { boff[i] = run; run += colsum[i]; }
    if (t == 255) boff[nbkt] = part[255];
}

__global__ void k_bapply(int* __restrict__ ghist, const int* __restrict__ boff, int nbkt) {
    int b = blockIdx.x * 256 + threadIdx.x;
    if (b >= nbkt) return;
    int run = boff[b];
    for (int i = 0; i < NBLK_H; i++) {
        int v = ghist[i * nbkt + b];
        ghist[i * nbkt + b] = run;
        run += v;
    }
}

__global__ __launch_bounds__(256) void k_scatter(const void* ei, int E, int N, int nbkt,
        const int* __restrict__ ghist, uint* __restrict__ pairs, const int* flag) {
    __shared__ int cur[NBKT_MAX];
    int tot = E + N;
    int epb = (tot + NBLK_H - 1) / NBLK_H;
    int e0 = blockIdx.x * epb, e1 = min(tot, e0 + epb);
    for (int i = threadIdx.x; i < nbkt; i += 256) cur[i] = ghist[blockIdx.x * nbkt + i];
    __syncthreads();
    int is64 = *flag;
    for (int e = e0 + threadIdx.x; e < e1; e += 256) {
        int src, dst;
        if (e < E) { src = ld_edge(ei, e, is64); dst = ld_edge(ei, (long)E + e, is64); }
        else { src = dst = e - E; }
        int pos = atomicAdd(&cur[dst >> 5], 1);
        pairs[pos] = ((uint)src << 5) | (uint)(dst & 31);
    }
}

// ---------- fused deg + scan + fill: one block per 32-node bucket ----------
__global__ __launch_bounds__(256) void k_fill3(const uint* __restrict__ pairs,
        const int* __restrict__ boff, int* __restrict__ rowptr,
        int* __restrict__ csr, int N, int nbkt) {
    __shared__ int cnt[32];
    __shared__ int base[32];
    __shared__ int cur[32];
    int b = blockIdx.x;
    int t = threadIdx.x;
    if (t < 32) { cnt[t] = 0; cur[t] = 0; }
    __syncthreads();
    int p0 = boff[b], p1 = boff[b + 1];
    for (int p = p0 + t; p < p1; p += 256)
        atomicAdd(&cnt[pairs[p] & 31], 1);
    __syncthreads();
    if (t < 32) {
        int pre = 0;
#pragma unroll
        for (int i = 0; i < 32; i++) pre += (i < t) ? cnt[i] : 0;
        base[t] = p0 + pre;
        int n = b * 32 + t;
        if (n < N) rowptr[n] = base[t];
    }
    if (b == 0 && t == 0) rowptr[N] = boff[nbkt];
    __syncthreads();
    for (int p = p0 + t; p < p1; p += 256) {
        uint v = pairs[p];
        int lo = v & 31;
        int pos = base[lo] + atomicAdd(&cur[lo], 1);
        csr[pos] = (int)(v >> 5);
    }
}

// ---------- Layer-1 aggregation + fused layer-2 projection ----------
__global__ __launch_bounds__(256) void k_agg1(const int* __restrict__ rowptr,
        const int* __restrict__ csr, const ushort* __restrict__ h1b,
        const float* __restrict__ als, const float* __restrict__ ald,
        const float* __restrict__ b1, const float* __restrict__ W2,
        const float* __restrict__ as2, const float* __restrict__ ad2,
        float* __restrict__ h2p, float* __restrict__ als2,
        float* __restrict__ ald2, int N) {
    int n = blockIdx.x * 4 + (threadIdx.x >> 6);
    if (n >= N) return;
    int lane = threadIdx.x & 63;
    int es = lane >> 3;      // edge slot
    int h = lane & 7;        // head; owns dims [8h, 8h+8)
    float aldh = ald[n * HEADS + h];
    int rs = rowptr[n], re = rowptr[n + 1];

    float acc[4][8];
    float den[4] = {0.f, 0.f, 0.f, 0.f};
#pragma unroll
    for (int q = 0; q < 4; ++q)
#pragma unroll
        for (int j = 0; j < 8; ++j) acc[q][j] = 0.f;

    int jb = rs;
    for (; jb + 32 <= re; jb += 32) {            // 4 chains in flight
        int s[4]; float e[4]; float p[4]; uint4 u[4];
#pragma unroll
        for (int q = 0; q < 4; ++q) s[q] = csr[jb + q * 8 + es];
#pragma unroll
        for (int q = 0; q < 4; ++q) {
            e[q] = als[s[q] * HEADS + h] + aldh;
            u[q] = *reinterpret_cast<const uint4*>(h1b + (long)s[q] * HD + h * 8);
        }
#pragma unroll
        for (int q = 0; q < 4; ++q) {
            e[q] = fmaxf(e[q], NEG * e[q]);
            p[q] = exp2f(e[q]);
        }
#pragma unroll
        for (int q = 0; q < 4; ++q) {
            acc[q][0] += p[q] * __uint_as_float(u[q].x << 16);
            acc[q][1] += p[q] * __uint_as_float(u[q].x & 0xffff0000u);
            acc[q][2] += p[q] * __uint_as_float(u[q].y << 16);
            acc[q][3] += p[q] * __uint_as_float(u[q].y & 0xffff0000u);
            acc[q][4] += p[q] * __uint_as_float(u[q].z << 16);
            acc[q][5] += p[q] * __uint_as_float(u[q].z & 0xffff0000u);
            acc[q][6] += p[q] * __uint_as_float(u[q].w << 16);
            acc[q][7] += p[q] * __uint_as_float(u[q].w & 0xffff0000u);
            den[q] += p[q];
        }
    }
    for (; jb + 16 <= re; jb += 16) {            // 2 chains
        int s[2]; float e[2]; float p[2]; uint4 u[2];
#pragma unroll
        for (int q = 0; q < 2; ++q) s[q] = csr[jb + q * 8 + es];
#pragma unroll
        for (int q = 0; q < 2; ++q) {
            e[q] = als[s[q] * HEADS + h] + aldh;
            u[q] = *reinterpret_cast<const uint4*>(h1b + (long)s[q] * HD + h * 8);
        }
#pragma unroll
        for (int q = 0; q < 2; ++q) {
            e[q] = fmaxf(e[q], NEG * e[q]);
            p[q] = exp2f(e[q]);
        }
#pragma unroll
        for (int q = 0; q < 2; ++q) {
            acc[q][0] += p[q] * __uint_as_float(u[q].x << 16);
            acc[q][1] += p[q] * __uint_as_float(u[q].x & 0xffff0000u);
            acc[q][2] += p[q] * __uint_as_float(u[q].y << 16);
            acc[q][3] += p[q] * __uint_as_float(u[q].y & 0xffff0000u);
            acc[q][4] += p[q] * __uint_as_float(u[q].z << 16);
            acc[q][5] += p[q] * __uint_as_float(u[q].z & 0xffff0000u);
            acc[q][6] += p[q] * __uint_as_float(u[q].w << 16);
            acc[q][7] += p[q] * __uint_as_float(u[q].w & 0xffff0000u);
            den[q] += p[q];
        }
    }
    for (; jb < re; jb += 8) {                   // guarded tail
        int eidx = jb + es;
        bool valid = (eidx < re);
        int s = csr[valid ? eidx : rs];
        float e = als[s * HEADS + h] + aldh;
        e = fmaxf(e, NEG * e);
        float p = valid ? exp2f(e) : 0.f;
        uint4 u = *reinterpret_cast<const uint4*>(h1b + (long)s * HD + h * 8);
        acc[0][0] += p * __uint_as_float(u.x << 16);
        acc[0][1] += p * __uint_as_float(u.x & 0xffff0000u);
        acc[0][2] += p * __uint_as_float(u.y << 16);
        acc[0][3] += p * __uint_as_float(u.y & 0xffff0000u);
        acc[0][4] += p * __uint_as_float(u.z << 16);
        acc[0][5] += p * __uint_as_float(u.z & 0xffff0000u);
        acc[0][6] += p * __uint_as_float(u.w << 16);
        acc[0][7] += p * __uint_as_float(u.w & 0xffff0000u);
        den[0] += p;
    }
    float a0 = (acc[0][0] + acc[1][0]) + (acc[2][0] + acc[3][0]);
    float a1 = (acc[0][1] + acc[1][1]) + (acc[2][1] + acc[3][1]);
    float a2 = (acc[0][2] + acc[1][2]) + (acc[2][2] + acc[3][2]);
    float a3 = (acc[0][3] + acc[1][3]) + (acc[2][3] + acc[3][3]);
    float a4 = (acc[0][4] + acc[1][4]) + (acc[2][4] + acc[3][4]);
    float a5 = (acc[0][5] + acc[1][5]) + (acc[2][5] + acc[3][5]);
    float a6 = (acc[0][6] + acc[1][6]) + (acc[2][6] + acc[3][6]);
    float a7 = (acc[0][7] + acc[1][7]) + (acc[2][7] + acc[3][7]);
    float dn = (den[0] + den[1]) + (den[2] + den[3]);
#pragma unroll
    for (int off = 8; off < 64; off <<= 1) {
        dn += __shfl_xor(dn, off);
        a0 += __shfl_xor(a0, off); a1 += __shfl_xor(a1, off);
        a2 += __shfl_xor(a2, off); a3 += __shfl_xor(a3, off);
        a4 += __shfl_xor(a4, off); a5 += __shfl_xor(a5, off);
        a6 += __shfl_xor(a6, off); a7 += __shfl_xor(a7, off);
    }
    float sel = (es < 4)
        ? ((es < 2) ? ((es == 0) ? a0 : a1) : ((es == 2) ? a2 : a3))
        : ((es < 6) ? ((es == 4) ? a4 : a5) : ((es == 6) ? a6 : a7));
    int d = h * 8 + es;
    float o = sel / (dn + EPSV) + b1[d];
    o = (o > 0.f) ? o : __expf(o) - 1.f;   // ELU
    // ---- fused gemm2
    float p0 = o * W2[d * CLS + 0];
    float p1 = o * W2[d * CLS + 1];
    float p2 = o * W2[d * CLS + 2];
#pragma unroll
    for (int off = 1; off < 64; off <<= 1) {
        p0 += __shfl_xor(p0, off);
        p1 += __shfl_xor(p1, off);
        p2 += __shfl_xor(p2, off);
    }
    if (lane == 0) {
        *reinterpret_cast<float4*>(h2p + (long)n * 4) = make_float4(p0, p1, p2, 0.f);
        als2[n] = (p0 * as2[0] + p1 * as2[1] + p2 * as2[2]) * LOG2E;
        ald2[n] = (p0 * ad2[0] + p1 * ad2[1] + p2 * ad2[2]) * LOG2E;
    }
}

// ---------- Layer-2 pull aggregation: 2 nodes/wave (32 lanes each) ----------
__global__ __launch_bounds__(256) void k_agg2(const int* __restrict__ rowptr,
        const int* __restrict__ csr, const float* __restrict__ h2p,
        const float* __restrict__ als2v, const float* __restrict__ ald2v,
        const float* __restrict__ b2, float* __restrict__ out, int N) {
    int n = blockIdx.x * 8 + (threadIdx.x >> 5);
    if (n >= N) return;
    int lane = threadIdx.x & 31;
    float aldv = ald2v[n];
    int rs = rowptr[n], re = rowptr[n + 1];
    float sum = 0.f, a0 = 0.f, a1 = 0.f, a2 = 0.f;
    for (int j = rs + lane; j < re; j += 32) {
        int s = csr[j];
        float e = als2v[s] + aldv;
        e = fmaxf(e, NEG * e);
        float p = exp2f(e);
        float4 hv = *reinterpret_cast<const float4*>(h2p + (long)s * 4);
        sum += p;
        a0 += p * hv.x;
        a1 += p * hv.y;
        a2 += p * hv.z;
    }
#pragma unroll
    for (int off = 1; off < 32; off <<= 1) {
        sum += __shfl_xor(sum, off);
        a0 += __shfl_xor(a0, off);
        a1 += __shfl_xor(a1, off);
        a2 += __shfl_xor(a2, off);
    }
    if (lane == 0) {
        float d = sum + EPSV;
        float v0 = a0 / d + b2[0], v1 = a1 / d + b2[1], v2 = a2 / d + b2[2];
        float mx = fmaxf(v0, fmaxf(v1, v2));
        float se = __expf(v0 - mx) + __expf(v1 - mx) + __expf(v2 - mx);
        float ls = mx + __logf(se);
        out[n * CLS + 0] = v0; out[n * CLS + 1] = v1; out[n * CLS + 2] = v2;
        long o2 = (long)N * CLS;
        out[o2 + n * CLS + 0] = v0 - ls;
        out[o2 + n * CLS + 1] = v1 - ls;
        out[o2 + n * CLS + 2] = v2 - ls;
    }
}

extern "C" void kernel_launch(void* const* d_in, const int* in_sizes, int n_in,
                              void* d_out, int out_size, void* d_ws, size_t ws_size,
                              hipStream_t stream) {
    const float* x   = (const float*)d_in[0];
    const void*  ei  = d_in[1];
    const float* W1  = (const float*)d_in[2];
    const float* as1 = (const float*)d_in[3];
    const float* ad1 = (const float*)d_in[4];
    const float* b1  = (const float*)d_in[5];
    const float* W2  = (const float*)d_in[6];
    const float* as2 = (const float*)d_in[7];
    const float* ad2 = (const float*)d_in[8];
    const float* b2  = (const float*)d_in[9];
    int N = in_sizes[0] / F_IN;
    int E = in_sizes[1] / 2;
    int tot = E + N;
    int nbkt = (N + 31) >> 5;

    char* w = (char*)d_ws;
    auto alloc = [&](size_t bytes) -> char* {
        char* p = w; w += (bytes + 255) & ~size_t(255); return p;
    };
    ushort* h1b    = (ushort*)alloc((size_t)N * HD * 2);
    float*  als1   = (float*)alloc((size_t)N * HEADS * 4);
    float*  ald1   = (float*)alloc((size_t)N * HEADS * 4);
    int*    rowptr = (int*)alloc((size_t)(N + 1) * 4);
    int*    csr    = (int*)alloc((size_t)tot * 4);
    float*  h2p    = (float*)alloc((size_t)N * 4 * 4);
    float*  als2   = (float*)alloc((size_t)N * 4);
    float*  ald2   = (float*)alloc((size_t)N * 4);
    ushort* W1b2   = (ushort*)alloc((size_t)16 * 64 * 32 * 2);
    int*    flag   = (int*)alloc(256);
    uint*   pairs  = (uint*)alloc((size_t)tot * 4);
    int*    ghist  = (int*)alloc((size_t)NBLK_H * nbkt * 4);
    int*    colsum = (int*)alloc((size_t)nbkt * 4);
    int*    boff   = (int*)alloc((size_t)(nbkt + 1) * 4);

    int gB = (N + 63) / 64;
    k_prepW<<<(16 * 64 * 32 + 255) / 256, 256, 0, stream>>>(W1, W1b2, (const int*)ei, flag);
    k_fatA<<<gB + NBLK_H, 256, 0, stream>>>(x, W1b2, as1, ad1, als1, ald1, h1b, N,
                                            ei, E, nbkt, ghist, flag);
    k_bsum<<<(nbkt + 255) / 256, 256, 0, stream>>>(ghist, colsum, nbkt);
    k_bscan2<<<1, 256, 0, stream>>>(colsum, boff, nbkt);
    k_bapply<<<(nbkt + 255) / 256, 256, 0, stream>>>(ghist, boff, nbkt);
    k_scatter<<<NBLK_H, 256, 0, stream>>>(ei, E, N, nbkt, ghist, pairs, flag);
    k_fill3<<<nbkt, 256, 0, stream>>>(pairs, boff, rowptr, csr, N, nbkt);
    k_agg1<<<(N + 3) / 4, 256, 0, stream>>>(rowptr, csr, h1b, als1, ald1, b1,
                                            W2, as2, ad2, h2p, als2, ald2, N);
    k_agg2<<<(N + 7) / 8, 256, 0, stream>>>(rowptr, csr, h2p, als2, ald2, b2,
                                            (float*)d_out, N);
}